// Round 2
// baseline (1246.587 us; speedup 1.0000x reference)
//
#include <hip/hip_runtime.h>
#include <hip/hip_bf16.h>

#define N_NODESC 50000
#define N_EDGESC 1600000
#define IN_DIMC 130
#define NUM_GRAPHSC 64
#define POOL_CHUNK 512

typedef __hip_bfloat16 bf16;

__device__ __forceinline__ float b2f(bf16 v) { return __bfloat162float(v); }
// flag-branched float load: fp32 buffer or bf16 buffer
__device__ __forceinline__ float ldf(const void* p, long i, int fp32) {
    return fp32 ? ((const float*)p)[i] : __bfloat162float(((const bf16*)p)[i]);
}

// ---------------- dtype detection ----------------
// flags[0]: 1 => float tensors are fp32, 0 => bf16
// flags[1]: 1 => int tensors are int64,  0 => int32
__global__ void detect_k(const void* __restrict__ prot,
                         const void* __restrict__ eidx,
                         int* __restrict__ flags) {
    if (blockIdx.x == 0 && threadIdx.x == 0) {
        // If buffer is fp32, bf16 elements at EVEN indices are fp32 low-mantissa
        // bits -> random exponents. If genuine bf16, they are sane N(0,1) values.
        const bf16* pb = (const bf16*)prot;
        int sane = 0;
        for (int i = 0; i < 64; ++i) {
            float a = fabsf(__bfloat162float(pb[2 * i]));
            if (a > 1e-8f && a < 1e4f) sane++;
        }
        flags[0] = (sane >= 48) ? 0 : 1;
        // int64 node ids < 2^31: high 32-bit words are all zero.
        const unsigned* u = (const unsigned*)eidx;
        int zhi = 0;
        for (int i = 0; i < 32; ++i)
            if (u[2 * i + 1] == 0u) zhi++;
        flags[1] = (zhi >= 30) ? 1 : 0;
    }
}

__global__ __launch_bounds__(256) void cvt_edges_k(const void* __restrict__ eidx,
                                                   int* __restrict__ edges32,
                                                   const int* __restrict__ flags) {
    const int i64f = flags[1];
    int i = blockIdx.x * 256 + threadIdx.x;
    if (i < 2 * N_EDGESC)
        edges32[i] = i64f ? (int)((const long long*)eidx)[i] : ((const int*)eidx)[i];
}

__global__ __launch_bounds__(256) void cvt_batch_k(const void* __restrict__ b,
                                                   int* __restrict__ b32,
                                                   const int* __restrict__ flags) {
    const int i64f = flags[1];
    int i = blockIdx.x * 256 + threadIdx.x;
    if (i < N_NODESC)
        b32[i] = i64f ? (int)((const long long*)b)[i] : ((const int*)b)[i];
}

__global__ __launch_bounds__(256) void zero_k(int* __restrict__ p, int n) {
    int i = blockIdx.x * 256 + threadIdx.x;
    if (i < n) p[i] = 0;
}

// ---------------- CSR build ----------------

__global__ __launch_bounds__(256) void hist_k(const int* __restrict__ dstv,
                                              int* __restrict__ deg) {
    int e = blockIdx.x * blockDim.x + threadIdx.x;
    if (e < N_EDGESC) atomicAdd(&deg[dstv[e]], 1);
}

__global__ __launch_bounds__(1024) void scan_k(const int* __restrict__ deg,
                                               int* __restrict__ row_start,
                                               int* __restrict__ cursor) {
    __shared__ int sums[1024];
    const int tid = threadIdx.x;
    const int CH = (N_NODESC + 1023) / 1024;   // 49
    int lo = tid * CH;
    int hi = lo + CH;
    if (hi > N_NODESC) hi = N_NODESC;
    if (lo > N_NODESC) lo = N_NODESC;
    int s = 0;
    for (int i = lo; i < hi; ++i) s += deg[i];
    sums[tid] = s;
    __syncthreads();
    for (int off = 1; off < 1024; off <<= 1) {
        int t = (tid >= off) ? sums[tid - off] : 0;
        __syncthreads();
        sums[tid] += t;
        __syncthreads();
    }
    int run = sums[tid] - s;   // exclusive prefix of this chunk
    for (int i = lo; i < hi; ++i) {
        row_start[i] = run;
        cursor[i] = run;
        run += deg[i];
    }
    if (tid == 1023) row_start[N_NODESC] = sums[1023];
}

__global__ __launch_bounds__(256) void scatter_k(const int* __restrict__ srcv,
                                                 const int* __restrict__ dstv,
                                                 int* __restrict__ cursor,
                                                 int* __restrict__ col) {
    int e = blockIdx.x * blockDim.x + threadIdx.x;
    if (e < N_EDGESC) {
        int pos = atomicAdd(&cursor[dstv[e]], 1);
        col[pos] = srcv[e];
    }
}

// ---------------- Layer 1: x@W1 (130->128) + fused attention logits ----------------

__global__ __launch_bounds__(128) void gemm1_k(
        const void* __restrict__ prot, const void* __restrict__ sp,
        const void* __restrict__ lri,  const void* __restrict__ W1,
        const void* __restrict__ a_src, const void* __restrict__ a_dst,
        const int* __restrict__ flags,
        float* __restrict__ xp1, float* __restrict__ alsrc, float* __restrict__ aldst) {
    const int fp32 = flags[0];
    const int n = blockIdx.x;
    const int j = threadIdx.x;
    __shared__ float xs[IN_DIMC];
    for (int k = j; k < IN_DIMC; k += 128) {
        float v;
        if (k < 64)      v = ldf(prot, (long)n * 64 + k, fp32);
        else if (k < 66) v = ldf(sp, (long)n * 2 + (k - 64), fp32);
        else             v = ldf(lri, (long)n * 64 + (k - 66), fp32);
        xs[k] = v;
    }
    __syncthreads();
    float acc = 0.f;
    for (int k = 0; k < IN_DIMC; ++k) acc += xs[k] * ldf(W1, k * 128 + j, fp32);
    xp1[(long)n * 128 + j] = acc;
    const int h = j >> 6, c = j & 63;
    float vs = acc * ldf(a_src, h * 64 + c, fp32);
    float vd = acc * ldf(a_dst, h * 64 + c, fp32);
    for (int off = 32; off > 0; off >>= 1) {
        vs += __shfl_down(vs, off, 64);
        vd += __shfl_down(vd, off, 64);
    }
    if (c == 0) { alsrc[n * 2 + h] = vs; aldst[n * 2 + h] = vd; }
}

// ---------------- Layer 1 aggregation: one wave per (node, head), online softmax ----------------

__global__ __launch_bounds__(256) void agg1_k(
        const int* __restrict__ row_start, const int* __restrict__ col,
        const float* __restrict__ xp1, const float* __restrict__ alsrc,
        const float* __restrict__ aldst, const void* __restrict__ b1,
        const int* __restrict__ flags, float* __restrict__ h1) {
    const int fp32 = flags[0];
    const int gw = blockIdx.x * 4 + (threadIdx.x >> 6);
    const int lane = threadIdx.x & 63;
    const int n = gw >> 1, h = gw & 1;
    if (n >= N_NODESC) return;
    const float ad = aldst[n * 2 + h];
    float e0 = alsrc[n * 2 + h] + ad;             // self-loop seeds the softmax
    e0 = e0 > 0.f ? e0 : 0.2f * e0;
    float m = e0, l = 1.f;
    float acc = xp1[(long)n * 128 + h * 64 + lane];
    const int beg = row_start[n], end = row_start[n + 1];
    for (int idx = beg; idx < end; ++idx) {
        int s = col[idx];
        float e = alsrc[s * 2 + h] + ad;
        e = e > 0.f ? e : 0.2f * e;
        float xw = xp1[(long)s * 128 + h * 64 + lane];
        if (e > m) {
            float sc = __expf(m - e);
            l *= sc; acc *= sc; m = e;
        }
        float p = __expf(e - m);
        l += p;
        acc += p * xw;
    }
    h1[(long)n * 128 + h * 64 + lane] = acc / l + ldf(b1, h * 64 + lane, fp32);
}

// ---------------- Layer 2: h1@W2 (128->64) + fused logits ----------------

__global__ __launch_bounds__(64) void gemm2_k(
        const float* __restrict__ h1, const void* __restrict__ W2,
        const void* __restrict__ a_src, const void* __restrict__ a_dst,
        const int* __restrict__ flags,
        float* __restrict__ xp2, float* __restrict__ alsrc, float* __restrict__ aldst) {
    const int fp32 = flags[0];
    const int n = blockIdx.x, j = threadIdx.x;
    __shared__ float xs[128];
    xs[j] = h1[(long)n * 128 + j];
    xs[j + 64] = h1[(long)n * 128 + 64 + j];
    __syncthreads();
    float acc = 0.f;
    for (int k = 0; k < 128; ++k) acc += xs[k] * ldf(W2, k * 64 + j, fp32);
    xp2[(long)n * 64 + j] = acc;
    float vs = acc * ldf(a_src, j, fp32);
    float vd = acc * ldf(a_dst, j, fp32);
    for (int off = 32; off > 0; off >>= 1) {
        vs += __shfl_down(vs, off, 64);
        vd += __shfl_down(vd, off, 64);
    }
    if (j == 0) { alsrc[n] = vs; aldst[n] = vd; }
}

// ---------------- Layer 2 aggregation: one wave per node ----------------

__global__ __launch_bounds__(256) void agg2_k(
        const int* __restrict__ row_start, const int* __restrict__ col,
        const float* __restrict__ xp2, const float* __restrict__ alsrc,
        const float* __restrict__ aldst, const void* __restrict__ b2v,
        const int* __restrict__ flags, float* __restrict__ h2) {
    const int fp32 = flags[0];
    const int n = blockIdx.x * 4 + (threadIdx.x >> 6);
    const int lane = threadIdx.x & 63;
    if (n >= N_NODESC) return;
    const float ad = aldst[n];
    float e0 = alsrc[n] + ad;
    e0 = e0 > 0.f ? e0 : 0.2f * e0;
    float m = e0, l = 1.f;
    float acc = xp2[(long)n * 64 + lane];
    const int beg = row_start[n], end = row_start[n + 1];
    for (int idx = beg; idx < end; ++idx) {
        int s = col[idx];
        float e = alsrc[s] + ad;
        e = e > 0.f ? e : 0.2f * e;
        float xw = xp2[(long)s * 64 + lane];
        if (e > m) {
            float sc = __expf(m - e);
            l *= sc; acc *= sc; m = e;
        }
        float p = __expf(e - m);
        l += p;
        acc += p * xw;
    }
    h2[(long)n * 64 + lane] = acc / l + ldf(b2v, lane, fp32);
}

// ---------------- mean pool over sorted batch (chunked, few atomics) ----------------

__global__ __launch_bounds__(64) void pool_k(const float* __restrict__ h2,
                                             const int* __restrict__ batch,
                                             float* __restrict__ pooled,
                                             float* __restrict__ counts) {
    const int c = threadIdx.x;
    int lo = blockIdx.x * POOL_CHUNK;
    int hi = lo + POOL_CHUNK;
    if (hi > N_NODESC) hi = N_NODESC;
    if (lo >= N_NODESC) return;
    int cur = batch[lo];
    float acc = 0.f;
    int cnt = 0;
    for (int i = lo; i < hi; ++i) {
        int g = batch[i];
        if (g != cur) {
            atomicAdd(&pooled[cur * 64 + c], acc);
            if (c == 0) atomicAdd(&counts[cur], (float)cnt);
            acc = 0.f; cnt = 0; cur = g;
        }
        acc += h2[(long)i * 64 + c];
        cnt++;
    }
    atomicAdd(&pooled[cur * 64 + c], acc);
    if (c == 0) atomicAdd(&counts[cur], (float)cnt);
}

// ---------------- decoder MLP ----------------

__global__ __launch_bounds__(64) void dec_k(const float* __restrict__ pooled,
                                            const float* __restrict__ counts,
                                            const void* __restrict__ Wd1, const void* __restrict__ bd1,
                                            const void* __restrict__ Wd2, const void* __restrict__ bd2,
                                            const int* __restrict__ flags,
                                            void* __restrict__ out) {
    const int fp32 = flags[0];
    const int g = blockIdx.x, j = threadIdx.x;
    __shared__ float p[64], dh[64];
    float cnt = counts[g];
    cnt = cnt < 1.f ? 1.f : cnt;
    p[j] = pooled[g * 64 + j] / cnt;
    __syncthreads();
    float acc = ldf(bd1, j, fp32);
    for (int k = 0; k < 64; ++k) acc += p[k] * ldf(Wd1, k * 64 + j, fp32);
    dh[j] = acc > 0.f ? acc : 0.f;
    __syncthreads();
    if (j < 32) {
        float o = ldf(bd2, j, fp32);
        for (int k = 0; k < 64; ++k) o += dh[k] * ldf(Wd2, k * 32 + j, fp32);
        if (fp32) ((float*)out)[g * 32 + j] = o;
        else      ((bf16*)out)[g * 32 + j] = __float2bfloat16(o);
    }
}

extern "C" void kernel_launch(void* const* d_in, const int* in_sizes, int n_in,
                              void* d_out, int out_size, void* d_ws, size_t ws_size,
                              hipStream_t stream) {
    (void)in_sizes; (void)n_in; (void)out_size; (void)ws_size;
    const void* prot = d_in[0];
    const void* sp   = d_in[1];
    const void* lri  = d_in[2];
    const void* eidx = d_in[3];
    const void* batch= d_in[4];
    const void* W1   = d_in[5];
    const void* as1  = d_in[6];
    const void* ad1  = d_in[7];
    const void* b1   = d_in[8];
    const void* W2   = d_in[9];
    const void* as2  = d_in[10];
    const void* ad2  = d_in[11];
    const void* b2v  = d_in[12];
    const void* Wd1  = d_in[13];
    const void* bd1  = d_in[14];
    const void* Wd2  = d_in[15];
    const void* bd2  = d_in[16];

    char* w = (char*)d_ws;
    auto alloc = [&](size_t bytes) -> void* {
        char* p = w;
        w += (bytes + 255) & ~(size_t)255;
        return (void*)p;
    };
    int*   flags     = (int*)alloc(2 * 4);
    int*   edges32   = (int*)alloc((size_t)2 * N_EDGESC * 4);
    int*   batch32   = (int*)alloc((size_t)N_NODESC * 4);
    int*   deg       = (int*)alloc((size_t)N_NODESC * 4);
    int*   row_start = (int*)alloc((size_t)(N_NODESC + 1) * 4);
    int*   cursor    = (int*)alloc((size_t)N_NODESC * 4);
    int*   col       = (int*)alloc((size_t)N_EDGESC * 4);
    float* xp1       = (float*)alloc((size_t)N_NODESC * 128 * 4);
    float* alsrc1    = (float*)alloc((size_t)N_NODESC * 2 * 4);
    float* aldst1    = (float*)alloc((size_t)N_NODESC * 2 * 4);
    float* h1        = (float*)alloc((size_t)N_NODESC * 128 * 4);
    float* xp2       = (float*)alloc((size_t)N_NODESC * 64 * 4);
    float* alsrc2    = (float*)alloc((size_t)N_NODESC * 4);
    float* aldst2    = (float*)alloc((size_t)N_NODESC * 4);
    float* h2        = (float*)alloc((size_t)N_NODESC * 64 * 4);
    float* pooled    = (float*)alloc((size_t)NUM_GRAPHSC * 64 * 4);
    float* counts    = (float*)alloc((size_t)NUM_GRAPHSC * 4);

    detect_k<<<1, 64, 0, stream>>>(prot, eidx, flags);
    cvt_edges_k<<<(2 * N_EDGESC + 255) / 256, 256, 0, stream>>>(eidx, edges32, flags);
    cvt_batch_k<<<(N_NODESC + 255) / 256, 256, 0, stream>>>(batch, batch32, flags);
    zero_k<<<(N_NODESC + 255) / 256, 256, 0, stream>>>(deg, N_NODESC);
    zero_k<<<(NUM_GRAPHSC * 64 + 255) / 256, 256, 0, stream>>>((int*)pooled, NUM_GRAPHSC * 64);
    zero_k<<<1, 256, 0, stream>>>((int*)counts, NUM_GRAPHSC);

    const int* srcv = edges32;
    const int* dstv = edges32 + N_EDGESC;

    hist_k<<<(N_EDGESC + 255) / 256, 256, 0, stream>>>(dstv, deg);
    scan_k<<<1, 1024, 0, stream>>>(deg, row_start, cursor);
    scatter_k<<<(N_EDGESC + 255) / 256, 256, 0, stream>>>(srcv, dstv, cursor, col);
    gemm1_k<<<N_NODESC, 128, 0, stream>>>(prot, sp, lri, W1, as1, ad1, flags, xp1, alsrc1, aldst1);
    agg1_k<<<(2 * N_NODESC + 3) / 4, 256, 0, stream>>>(row_start, col, xp1, alsrc1, aldst1, b1, flags, h1);
    gemm2_k<<<N_NODESC, 64, 0, stream>>>(h1, W2, as2, ad2, flags, xp2, alsrc2, aldst2);
    agg2_k<<<(N_NODESC + 3) / 4, 256, 0, stream>>>(row_start, col, xp2, alsrc2, aldst2, b2v, flags, h2);
    pool_k<<<(N_NODESC + POOL_CHUNK - 1) / POOL_CHUNK, 64, 0, stream>>>(h2, batch32, pooled, counts);
    dec_k<<<NUM_GRAPHSC, 64, 0, stream>>>(pooled, counts, Wd1, bd1, Wd2, bd2, flags, d_out);
}

// Round 3
// 855.459 us; speedup vs baseline: 1.4572x; 1.4572x over previous
//
#include <hip/hip_runtime.h>
#include <hip/hip_bf16.h>

#define N_NODESC 50000
#define N_EDGESC 1600000
#define IN_DIMC 130
#define NUM_GRAPHSC 64
#define POOL_CHUNK 128

typedef __hip_bfloat16 bf16;

__device__ __forceinline__ float b2f(bf16 v) { return __bfloat162float(v); }
// flag-branched float load: fp32 buffer or bf16 buffer
__device__ __forceinline__ float ldf(const void* p, long i, int fp32) {
    return fp32 ? ((const float*)p)[i] : __bfloat162float(((const bf16*)p)[i]);
}

// ---------------- dtype detection ----------------
// flags[0]: 1 => float tensors are fp32, 0 => bf16
// flags[1]: 1 => int tensors are int64,  0 => int32
__global__ void detect_k(const void* __restrict__ prot,
                         const void* __restrict__ eidx,
                         int* __restrict__ flags) {
    if (blockIdx.x == 0 && threadIdx.x == 0) {
        const bf16* pb = (const bf16*)prot;
        int sane = 0;
        for (int i = 0; i < 64; ++i) {
            float a = fabsf(__bfloat162float(pb[2 * i]));
            if (a > 1e-8f && a < 1e4f) sane++;
        }
        flags[0] = (sane >= 48) ? 0 : 1;
        const unsigned* u = (const unsigned*)eidx;
        int zhi = 0;
        for (int i = 0; i < 32; ++i)
            if (u[2 * i + 1] == 0u) zhi++;
        flags[1] = (zhi >= 30) ? 1 : 0;
    }
}

__global__ __launch_bounds__(256) void cvt_edges_k(const void* __restrict__ eidx,
                                                   int* __restrict__ edges32,
                                                   const int* __restrict__ flags) {
    const int i64f = flags[1];
    int i = blockIdx.x * 256 + threadIdx.x;
    if (i < 2 * N_EDGESC)
        edges32[i] = i64f ? (int)((const long long*)eidx)[i] : ((const int*)eidx)[i];
}

__global__ __launch_bounds__(256) void cvt_batch_k(const void* __restrict__ b,
                                                   int* __restrict__ b32,
                                                   const int* __restrict__ flags) {
    const int i64f = flags[1];
    int i = blockIdx.x * 256 + threadIdx.x;
    if (i < N_NODESC)
        b32[i] = i64f ? (int)((const long long*)b)[i] : ((const int*)b)[i];
}

__global__ __launch_bounds__(256) void zero_k(int* __restrict__ p, int n) {
    int i = blockIdx.x * 256 + threadIdx.x;
    if (i < n) p[i] = 0;
}

// ---------------- CSR build ----------------

__global__ __launch_bounds__(256) void hist_k(const int* __restrict__ dstv,
                                              int* __restrict__ deg) {
    int e = blockIdx.x * blockDim.x + threadIdx.x;
    if (e < N_EDGESC) atomicAdd(&deg[dstv[e]], 1);
}

__global__ __launch_bounds__(1024) void scan_k(const int* __restrict__ deg,
                                               int* __restrict__ row_start,
                                               int* __restrict__ cursor) {
    __shared__ int sums[1024];
    const int tid = threadIdx.x;
    const int CH = (N_NODESC + 1023) / 1024;   // 49
    int lo = tid * CH;
    int hi = lo + CH;
    if (hi > N_NODESC) hi = N_NODESC;
    if (lo > N_NODESC) lo = N_NODESC;
    int s = 0;
    for (int i = lo; i < hi; ++i) s += deg[i];
    sums[tid] = s;
    __syncthreads();
    for (int off = 1; off < 1024; off <<= 1) {
        int t = (tid >= off) ? sums[tid - off] : 0;
        __syncthreads();
        sums[tid] += t;
        __syncthreads();
    }
    int run = sums[tid] - s;   // exclusive prefix of this chunk
    for (int i = lo; i < hi; ++i) {
        row_start[i] = run;
        cursor[i] = run;
        run += deg[i];
    }
    if (tid == 1023) row_start[N_NODESC] = sums[1023];
}

__global__ __launch_bounds__(256) void scatter_k(const int* __restrict__ srcv,
                                                 const int* __restrict__ dstv,
                                                 int* __restrict__ cursor,
                                                 int* __restrict__ col) {
    int e = blockIdx.x * blockDim.x + threadIdx.x;
    if (e < N_EDGESC) {
        int pos = atomicAdd(&cursor[dstv[e]], 1);
        col[pos] = srcv[e];
    }
}

// ---------------- Layer 1: x@W1 (130->128) + fused attention logits ----------------

__global__ __launch_bounds__(128) void gemm1_k(
        const void* __restrict__ prot, const void* __restrict__ sp,
        const void* __restrict__ lri,  const void* __restrict__ W1,
        const void* __restrict__ a_src, const void* __restrict__ a_dst,
        const int* __restrict__ flags,
        float* __restrict__ xp1, float* __restrict__ alsrc, float* __restrict__ aldst) {
    const int fp32 = flags[0];
    const int n = blockIdx.x;
    const int j = threadIdx.x;
    __shared__ float xs[IN_DIMC];
    for (int k = j; k < IN_DIMC; k += 128) {
        float v;
        if (k < 64)      v = ldf(prot, (long)n * 64 + k, fp32);
        else if (k < 66) v = ldf(sp, (long)n * 2 + (k - 64), fp32);
        else             v = ldf(lri, (long)n * 64 + (k - 66), fp32);
        xs[k] = v;
    }
    __syncthreads();
    float acc = 0.f;
    for (int k = 0; k < IN_DIMC; ++k) acc += xs[k] * ldf(W1, k * 128 + j, fp32);
    xp1[(long)n * 128 + j] = acc;
    const int h = j >> 6, c = j & 63;
    float vs = acc * ldf(a_src, h * 64 + c, fp32);
    float vd = acc * ldf(a_dst, h * 64 + c, fp32);
    for (int off = 32; off > 0; off >>= 1) {
        vs += __shfl_down(vs, off, 64);
        vd += __shfl_down(vd, off, 64);
    }
    if (c == 0) { alsrc[n * 2 + h] = vs; aldst[n * 2 + h] = vd; }
}

// ---------------- Layer 1 aggregation: chunked lane-parallel online softmax ----------------
// One wave per (node, head). Edges processed 64 at a time: lane j owns edge
// base+j's logit; (p, src) staged in per-wave LDS; accumulation loop issues
// independent 256B row loads (pipelined), 1 broadcast ds_read_b64 per edge.

__global__ __launch_bounds__(256) void agg1_k(
        const int* __restrict__ row_start, const int* __restrict__ col,
        const float* __restrict__ xp1, const float* __restrict__ alsrc,
        const float* __restrict__ aldst, const void* __restrict__ b1,
        const int* __restrict__ flags, float* __restrict__ h1) {
    const int fp32 = flags[0];
    const int wid = threadIdx.x >> 6;
    const int lane = threadIdx.x & 63;
    const int gw = blockIdx.x * 4 + wid;
    const int n = gw >> 1, h = gw & 1;
    __shared__ float2 pbuf[4][64];
    if (n >= N_NODESC) return;
    float2* mybuf = pbuf[wid];
    const float ad = aldst[n * 2 + h];
    float e0 = alsrc[n * 2 + h] + ad;             // self-loop seeds the softmax
    e0 = e0 > 0.f ? e0 : 0.2f * e0;
    float m = e0, l = 1.f;
    float acc = xp1[(long)n * 128 + h * 64 + lane];
    const int beg = row_start[n], end = row_start[n + 1];
    for (int base = beg; base < end; base += 64) {
        const int idx = base + lane;
        const int valid = idx < end;
        int s = valid ? col[idx] : 0;
        float e = -3.0e38f;
        if (valid) {
            float t = alsrc[s * 2 + h] + ad;
            e = t > 0.f ? t : 0.2f * t;
        }
        float M = e;
        #pragma unroll
        for (int off = 32; off; off >>= 1) M = fmaxf(M, __shfl_xor(M, off, 64));
        if (M > m) { float sc = __expf(m - M); l *= sc; acc *= sc; m = M; }
        float p = valid ? __expf(e - m) : 0.f;
        float ps = p;
        #pragma unroll
        for (int off = 32; off; off >>= 1) ps += __shfl_xor(ps, off, 64);
        l += ps;
        mybuf[lane] = make_float2(p, __int_as_float(s));
        int cnt = end - base; if (cnt > 64) cnt = 64;
        int j = 0;
        for (; j + 4 <= cnt; j += 4) {
            float2 a0 = mybuf[j], a1 = mybuf[j + 1], a2 = mybuf[j + 2], a3 = mybuf[j + 3];
            float x0 = xp1[(long)__float_as_int(a0.y) * 128 + h * 64 + lane];
            float x1 = xp1[(long)__float_as_int(a1.y) * 128 + h * 64 + lane];
            float x2 = xp1[(long)__float_as_int(a2.y) * 128 + h * 64 + lane];
            float x3 = xp1[(long)__float_as_int(a3.y) * 128 + h * 64 + lane];
            acc = fmaf(a0.x, x0, acc);
            acc = fmaf(a1.x, x1, acc);
            acc = fmaf(a2.x, x2, acc);
            acc = fmaf(a3.x, x3, acc);
        }
        for (; j < cnt; ++j) {
            float2 a = mybuf[j];
            acc = fmaf(a.x, xp1[(long)__float_as_int(a.y) * 128 + h * 64 + lane], acc);
        }
    }
    h1[(long)n * 128 + h * 64 + lane] = acc / l + ldf(b1, h * 64 + lane, fp32);
}

// ---------------- Layer 2: h1@W2 (128->64) + fused logits ----------------

__global__ __launch_bounds__(64) void gemm2_k(
        const float* __restrict__ h1, const void* __restrict__ W2,
        const void* __restrict__ a_src, const void* __restrict__ a_dst,
        const int* __restrict__ flags,
        float* __restrict__ xp2, float* __restrict__ alsrc, float* __restrict__ aldst) {
    const int fp32 = flags[0];
    const int n = blockIdx.x, j = threadIdx.x;
    __shared__ float xs[128];
    xs[j] = h1[(long)n * 128 + j];
    xs[j + 64] = h1[(long)n * 128 + 64 + j];
    __syncthreads();
    float acc = 0.f;
    for (int k = 0; k < 128; ++k) acc += xs[k] * ldf(W2, k * 64 + j, fp32);
    xp2[(long)n * 64 + j] = acc;
    float vs = acc * ldf(a_src, j, fp32);
    float vd = acc * ldf(a_dst, j, fp32);
    for (int off = 32; off > 0; off >>= 1) {
        vs += __shfl_down(vs, off, 64);
        vd += __shfl_down(vd, off, 64);
    }
    if (j == 0) { alsrc[n] = vs; aldst[n] = vd; }
}

// ---------------- Layer 2 aggregation: chunked lane-parallel, one wave per node ----------------

__global__ __launch_bounds__(256) void agg2_k(
        const int* __restrict__ row_start, const int* __restrict__ col,
        const float* __restrict__ xp2, const float* __restrict__ alsrc,
        const float* __restrict__ aldst, const void* __restrict__ b2v,
        const int* __restrict__ flags, float* __restrict__ h2) {
    const int fp32 = flags[0];
    const int wid = threadIdx.x >> 6;
    const int lane = threadIdx.x & 63;
    const int n = blockIdx.x * 4 + wid;
    __shared__ float2 pbuf[4][64];
    if (n >= N_NODESC) return;
    float2* mybuf = pbuf[wid];
    const float ad = aldst[n];
    float e0 = alsrc[n] + ad;
    e0 = e0 > 0.f ? e0 : 0.2f * e0;
    float m = e0, l = 1.f;
    float acc = xp2[(long)n * 64 + lane];
    const int beg = row_start[n], end = row_start[n + 1];
    for (int base = beg; base < end; base += 64) {
        const int idx = base + lane;
        const int valid = idx < end;
        int s = valid ? col[idx] : 0;
        float e = -3.0e38f;
        if (valid) {
            float t = alsrc[s] + ad;
            e = t > 0.f ? t : 0.2f * t;
        }
        float M = e;
        #pragma unroll
        for (int off = 32; off; off >>= 1) M = fmaxf(M, __shfl_xor(M, off, 64));
        if (M > m) { float sc = __expf(m - M); l *= sc; acc *= sc; m = M; }
        float p = valid ? __expf(e - m) : 0.f;
        float ps = p;
        #pragma unroll
        for (int off = 32; off; off >>= 1) ps += __shfl_xor(ps, off, 64);
        l += ps;
        mybuf[lane] = make_float2(p, __int_as_float(s));
        int cnt = end - base; if (cnt > 64) cnt = 64;
        int j = 0;
        for (; j + 4 <= cnt; j += 4) {
            float2 a0 = mybuf[j], a1 = mybuf[j + 1], a2 = mybuf[j + 2], a3 = mybuf[j + 3];
            float x0 = xp2[(long)__float_as_int(a0.y) * 64 + lane];
            float x1 = xp2[(long)__float_as_int(a1.y) * 64 + lane];
            float x2 = xp2[(long)__float_as_int(a2.y) * 64 + lane];
            float x3 = xp2[(long)__float_as_int(a3.y) * 64 + lane];
            acc = fmaf(a0.x, x0, acc);
            acc = fmaf(a1.x, x1, acc);
            acc = fmaf(a2.x, x2, acc);
            acc = fmaf(a3.x, x3, acc);
        }
        for (; j < cnt; ++j) {
            float2 a = mybuf[j];
            acc = fmaf(a.x, xp2[(long)__float_as_int(a.y) * 64 + lane], acc);
        }
    }
    h2[(long)n * 64 + lane] = acc / l + ldf(b2v, lane, fp32);
}

// ---------------- mean pool over sorted batch (chunked, few atomics) ----------------

__global__ __launch_bounds__(64) void pool_k(const float* __restrict__ h2,
                                             const int* __restrict__ batch,
                                             float* __restrict__ pooled,
                                             float* __restrict__ counts) {
    const int c = threadIdx.x;
    int lo = blockIdx.x * POOL_CHUNK;
    int hi = lo + POOL_CHUNK;
    if (hi > N_NODESC) hi = N_NODESC;
    if (lo >= N_NODESC) return;
    int cur = batch[lo];
    float acc = 0.f;
    int cnt = 0;
    for (int i = lo; i < hi; ++i) {
        int g = batch[i];
        if (g != cur) {
            atomicAdd(&pooled[cur * 64 + c], acc);
            if (c == 0) atomicAdd(&counts[cur], (float)cnt);
            acc = 0.f; cnt = 0; cur = g;
        }
        acc += h2[(long)i * 64 + c];
        cnt++;
    }
    atomicAdd(&pooled[cur * 64 + c], acc);
    if (c == 0) atomicAdd(&counts[cur], (float)cnt);
}

// ---------------- decoder MLP ----------------

__global__ __launch_bounds__(64) void dec_k(const float* __restrict__ pooled,
                                            const float* __restrict__ counts,
                                            const void* __restrict__ Wd1, const void* __restrict__ bd1,
                                            const void* __restrict__ Wd2, const void* __restrict__ bd2,
                                            const int* __restrict__ flags,
                                            void* __restrict__ out) {
    const int fp32 = flags[0];
    const int g = blockIdx.x, j = threadIdx.x;
    __shared__ float p[64], dh[64];
    float cnt = counts[g];
    cnt = cnt < 1.f ? 1.f : cnt;
    p[j] = pooled[g * 64 + j] / cnt;
    __syncthreads();
    float acc = ldf(bd1, j, fp32);
    for (int k = 0; k < 64; ++k) acc += p[k] * ldf(Wd1, k * 64 + j, fp32);
    dh[j] = acc > 0.f ? acc : 0.f;
    __syncthreads();
    if (j < 32) {
        float o = ldf(bd2, j, fp32);
        for (int k = 0; k < 64; ++k) o += dh[k] * ldf(Wd2, k * 32 + j, fp32);
        if (fp32) ((float*)out)[g * 32 + j] = o;
        else      ((bf16*)out)[g * 32 + j] = __float2bfloat16(o);
    }
}

extern "C" void kernel_launch(void* const* d_in, const int* in_sizes, int n_in,
                              void* d_out, int out_size, void* d_ws, size_t ws_size,
                              hipStream_t stream) {
    (void)in_sizes; (void)n_in; (void)out_size; (void)ws_size;
    const void* prot = d_in[0];
    const void* sp   = d_in[1];
    const void* lri  = d_in[2];
    const void* eidx = d_in[3];
    const void* batch= d_in[4];
    const void* W1   = d_in[5];
    const void* as1  = d_in[6];
    const void* ad1  = d_in[7];
    const void* b1   = d_in[8];
    const void* W2   = d_in[9];
    const void* as2  = d_in[10];
    const void* ad2  = d_in[11];
    const void* b2v  = d_in[12];
    const void* Wd1  = d_in[13];
    const void* bd1  = d_in[14];
    const void* Wd2  = d_in[15];
    const void* bd2  = d_in[16];

    char* w = (char*)d_ws;
    auto alloc = [&](size_t bytes) -> void* {
        char* p = w;
        w += (bytes + 255) & ~(size_t)255;
        return (void*)p;
    };
    int*   flags     = (int*)alloc(2 * 4);
    int*   edges32   = (int*)alloc((size_t)2 * N_EDGESC * 4);
    int*   batch32   = (int*)alloc((size_t)N_NODESC * 4);
    int*   deg       = (int*)alloc((size_t)N_NODESC * 4);
    int*   row_start = (int*)alloc((size_t)(N_NODESC + 1) * 4);
    int*   cursor    = (int*)alloc((size_t)N_NODESC * 4);
    int*   col       = (int*)alloc((size_t)N_EDGESC * 4);
    float* xp1       = (float*)alloc((size_t)N_NODESC * 128 * 4);
    float* alsrc1    = (float*)alloc((size_t)N_NODESC * 2 * 4);
    float* aldst1    = (float*)alloc((size_t)N_NODESC * 2 * 4);
    float* h1        = (float*)alloc((size_t)N_NODESC * 128 * 4);
    float* xp2       = (float*)alloc((size_t)N_NODESC * 64 * 4);
    float* alsrc2    = (float*)alloc((size_t)N_NODESC * 4);
    float* aldst2    = (float*)alloc((size_t)N_NODESC * 4);
    float* h2        = (float*)alloc((size_t)N_NODESC * 64 * 4);
    float* pooled    = (float*)alloc((size_t)NUM_GRAPHSC * 64 * 4);
    float* counts    = (float*)alloc((size_t)NUM_GRAPHSC * 4);

    detect_k<<<1, 64, 0, stream>>>(prot, eidx, flags);
    cvt_edges_k<<<(2 * N_EDGESC + 255) / 256, 256, 0, stream>>>(eidx, edges32, flags);
    cvt_batch_k<<<(N_NODESC + 255) / 256, 256, 0, stream>>>(batch, batch32, flags);
    zero_k<<<(N_NODESC + 255) / 256, 256, 0, stream>>>(deg, N_NODESC);
    zero_k<<<(NUM_GRAPHSC * 64 + 255) / 256, 256, 0, stream>>>((int*)pooled, NUM_GRAPHSC * 64);
    zero_k<<<1, 256, 0, stream>>>((int*)counts, NUM_GRAPHSC);

    const int* srcv = edges32;
    const int* dstv = edges32 + N_EDGESC;

    hist_k<<<(N_EDGESC + 255) / 256, 256, 0, stream>>>(dstv, deg);
    scan_k<<<1, 1024, 0, stream>>>(deg, row_start, cursor);
    scatter_k<<<(N_EDGESC + 255) / 256, 256, 0, stream>>>(srcv, dstv, cursor, col);
    gemm1_k<<<N_NODESC, 128, 0, stream>>>(prot, sp, lri, W1, as1, ad1, flags, xp1, alsrc1, aldst1);
    agg1_k<<<(2 * N_NODESC + 3) / 4, 256, 0, stream>>>(row_start, col, xp1, alsrc1, aldst1, b1, flags, h1);
    gemm2_k<<<N_NODESC, 64, 0, stream>>>(h1, W2, as2, ad2, flags, xp2, alsrc2, aldst2);
    agg2_k<<<(N_NODESC + 3) / 4, 256, 0, stream>>>(row_start, col, xp2, alsrc2, aldst2, b2v, flags, h2);
    pool_k<<<(N_NODESC + POOL_CHUNK - 1) / POOL_CHUNK, 64, 0, stream>>>(h2, batch32, pooled, counts);
    dec_k<<<NUM_GRAPHSC, 64, 0, stream>>>(pooled, counts, Wd1, bd1, Wd2, bd2, flags, d_out);
}

// Round 4
// 744.191 us; speedup vs baseline: 1.6751x; 1.1495x over previous
//
#include <hip/hip_runtime.h>
#include <hip/hip_bf16.h>

#define N_NODESC 50000
#define N_EDGESC 1600000
#define IN_DIMC 130
#define NUM_GRAPHSC 64
#define POOL_CHUNK 128

typedef __hip_bfloat16 bf16;
typedef short short8 __attribute__((ext_vector_type(8)));
typedef float floatx4 __attribute__((ext_vector_type(4)));

__device__ __forceinline__ float b2f(bf16 v) { return __bfloat162float(v); }
__device__ __forceinline__ float ldf(const void* p, long i, int fp32) {
    return fp32 ? ((const float*)p)[i] : __bfloat162float(((const bf16*)p)[i]);
}
__device__ __forceinline__ short f2s(float v) {
    bf16 h = __float2bfloat16(v);
    return *(short*)&h;
}

// ---------------- dtype detection ----------------
__global__ void detect_k(const void* __restrict__ prot,
                         const void* __restrict__ eidx,
                         int* __restrict__ flags) {
    if (blockIdx.x == 0 && threadIdx.x == 0) {
        const bf16* pb = (const bf16*)prot;
        int sane = 0;
        for (int i = 0; i < 64; ++i) {
            float a = fabsf(__bfloat162float(pb[2 * i]));
            if (a > 1e-8f && a < 1e4f) sane++;
        }
        flags[0] = (sane >= 48) ? 0 : 1;
        const unsigned* u = (const unsigned*)eidx;
        int zhi = 0;
        for (int i = 0; i < 32; ++i)
            if (u[2 * i + 1] == 0u) zhi++;
        flags[1] = (zhi >= 30) ? 1 : 0;
    }
}

__global__ __launch_bounds__(256) void cvt_edges_k(const void* __restrict__ eidx,
                                                   int* __restrict__ edges32,
                                                   const int* __restrict__ flags) {
    const int i64f = flags[1];
    int i = blockIdx.x * 256 + threadIdx.x;
    if (i < 2 * N_EDGESC)
        edges32[i] = i64f ? (int)((const long long*)eidx)[i] : ((const int*)eidx)[i];
}

__global__ __launch_bounds__(256) void cvt_batch_k(const void* __restrict__ b,
                                                   int* __restrict__ b32,
                                                   const int* __restrict__ flags) {
    const int i64f = flags[1];
    int i = blockIdx.x * 256 + threadIdx.x;
    if (i < N_NODESC)
        b32[i] = i64f ? (int)((const long long*)b)[i] : ((const int*)b)[i];
}

__global__ __launch_bounds__(256) void zero_k(int* __restrict__ p, int n) {
    int i = blockIdx.x * 256 + threadIdx.x;
    if (i < n) p[i] = 0;
}

// ---------------- CSR build ----------------

__global__ __launch_bounds__(256) void hist_k(const int* __restrict__ dstv,
                                              int* __restrict__ deg) {
    int e = blockIdx.x * blockDim.x + threadIdx.x;
    if (e < N_EDGESC) atomicAdd(&deg[dstv[e]], 1);
}

__global__ __launch_bounds__(1024) void scan_k(const int* __restrict__ deg,
                                               int* __restrict__ row_start,
                                               int* __restrict__ cursor) {
    __shared__ int sums[1024];
    const int tid = threadIdx.x;
    const int CH = (N_NODESC + 1023) / 1024;
    int lo = tid * CH;
    int hi = lo + CH;
    if (hi > N_NODESC) hi = N_NODESC;
    if (lo > N_NODESC) lo = N_NODESC;
    int s = 0;
    for (int i = lo; i < hi; ++i) s += deg[i];
    sums[tid] = s;
    __syncthreads();
    for (int off = 1; off < 1024; off <<= 1) {
        int t = (tid >= off) ? sums[tid - off] : 0;
        __syncthreads();
        sums[tid] += t;
        __syncthreads();
    }
    int run = sums[tid] - s;
    for (int i = lo; i < hi; ++i) {
        row_start[i] = run;
        cursor[i] = run;
        run += deg[i];
    }
    if (tid == 1023) row_start[N_NODESC] = sums[1023];
}

__global__ __launch_bounds__(256) void scatter_k(const int* __restrict__ srcv,
                                                 const int* __restrict__ dstv,
                                                 int* __restrict__ cursor,
                                                 int* __restrict__ col) {
    int e = blockIdx.x * blockDim.x + threadIdx.x;
    if (e < N_EDGESC) {
        int pos = atomicAdd(&cursor[dstv[e]], 1);
        col[pos] = srcv[e];
    }
}

// ---------------- Layer 1 GEMM via MFMA: x[50000,130] @ W1[130,128] ----------------
// 32 nodes/block, 256 threads = 4 waves. K=128 via 4 MFMA steps; k=128,129 via
// rank-2 VALU update in the epilogue. W1 staged in B-frag-major LDS layout.

__global__ __launch_bounds__(256) void gemm1_k(
        const void* __restrict__ prot, const void* __restrict__ sp,
        const void* __restrict__ lri,  const void* __restrict__ W1,
        const int* __restrict__ flags, float* __restrict__ xp1) {
    const int fp32 = flags[0];
    const int tid = threadIdx.x;
    const int nb = blockIdx.x * 32;
    __shared__ __align__(16) short W1s[16384];      // (c,t,q,n,j) frag-major, K<128
    __shared__ float W1r[2][128];                   // rows 128,129
    __shared__ __align__(16) short xs[32][136];     // node rows, padded (2-way banks)
    __shared__ float xsp[32][2];                    // spatial remainder (x[128],x[129])

    // stage W1 K<128 part into frag-major layout
    #pragma unroll
    for (int i = 0; i < 64; ++i) {
        int idx = i * 256 + tid;                    // 16384
        int k = idx >> 7, n = idx & 127;
        float v = ldf(W1, (long)k * 128 + n, fp32);
        int c = n >> 4, nn = n & 15, t = k >> 5, q = (k >> 3) & 3, j = k & 7;
        W1s[(((c * 4 + t) * 4 + q) * 16 + nn) * 8 + j] = f2s(v);
    }
    // remainder rows
    W1r[tid >> 7][tid & 127] = ldf(W1, (long)(128 + (tid >> 7)) * 128 + (tid & 127), fp32);
    // stage x tile (k<128) as bf16
    #pragma unroll
    for (int i = 0; i < 16; ++i) {
        int idx = i * 256 + tid;                    // 4096
        int r = idx >> 7, k = idx & 127;
        int g = nb + r;
        float v = 0.f;
        if (g < N_NODESC) {
            if (k < 64)      v = ldf(prot, (long)g * 64 + k, fp32);
            else if (k < 66) v = ldf(sp, (long)g * 2 + (k - 64), fp32);
            else             v = ldf(lri, (long)g * 64 + (k - 66), fp32);
        }
        xs[r][k] = f2s(v);
    }
    if (tid < 64) {
        int r = tid >> 1, which = tid & 1;
        int g = nb + r;
        xsp[r][which] = (g < N_NODESC) ? ldf(lri, (long)g * 64 + 62 + which, fp32) : 0.f;
    }
    __syncthreads();

    const int wid = tid >> 6, lane = tid & 63;
    const int quad = lane >> 4, l16 = lane & 15;
    floatx4 acc[2][2];
    #pragma unroll
    for (int a = 0; a < 2; ++a)
        #pragma unroll
        for (int b = 0; b < 2; ++b) acc[a][b] = (floatx4){0.f, 0.f, 0.f, 0.f};

    const int c0 = 2 * wid;
    #pragma unroll
    for (int t = 0; t < 4; ++t) {
        short8 a0 = *(const short8*)&xs[l16][t * 32 + quad * 8];
        short8 a1 = *(const short8*)&xs[16 + l16][t * 32 + quad * 8];
        short8 b0 = *(const short8*)&W1s[(((c0 * 4 + t) * 4 + quad) * 16 + l16) * 8];
        short8 b1 = *(const short8*)&W1s[((((c0 + 1) * 4 + t) * 4 + quad) * 16 + l16) * 8];
        acc[0][0] = __builtin_amdgcn_mfma_f32_16x16x32_bf16(a0, b0, acc[0][0], 0, 0, 0);
        acc[0][1] = __builtin_amdgcn_mfma_f32_16x16x32_bf16(a0, b1, acc[0][1], 0, 0, 0);
        acc[1][0] = __builtin_amdgcn_mfma_f32_16x16x32_bf16(a1, b0, acc[1][0], 0, 0, 0);
        acc[1][1] = __builtin_amdgcn_mfma_f32_16x16x32_bf16(a1, b1, acc[1][1], 0, 0, 0);
    }
    #pragma unroll
    for (int rt = 0; rt < 2; ++rt) {
        #pragma unroll
        for (int ci = 0; ci < 2; ++ci) {
            int colg = (c0 + ci) * 16 + l16;
            float w0 = W1r[0][colg], w1 = W1r[1][colg];
            #pragma unroll
            for (int reg = 0; reg < 4; ++reg) {
                int row = rt * 16 + quad * 4 + reg;
                int g = nb + row;
                if (g < N_NODESC) {
                    float v = acc[rt][ci][reg] + xsp[row][0] * w0 + xsp[row][1] * w1;
                    xp1[(long)g * 128 + colg] = v;
                }
            }
        }
    }
}

// ---------------- Layer 1 attention logits ----------------

__global__ __launch_bounds__(256) void logits1_k(
        const float* __restrict__ xp1, const void* __restrict__ as1,
        const void* __restrict__ ad1, const int* __restrict__ flags,
        float* __restrict__ alsrc, float* __restrict__ aldst) {
    const int fp32 = flags[0];
    const int wid = threadIdx.x >> 6, lane = threadIdx.x & 63;
    const int n = blockIdx.x * 4 + wid;
    if (n >= N_NODESC) return;
    float v0 = xp1[(long)n * 128 + lane];
    float v1 = xp1[(long)n * 128 + 64 + lane];
    float s0 = v0 * ldf(as1, lane, fp32), d0 = v0 * ldf(ad1, lane, fp32);
    float s1 = v1 * ldf(as1, 64 + lane, fp32), d1 = v1 * ldf(ad1, 64 + lane, fp32);
    #pragma unroll
    for (int off = 32; off; off >>= 1) {
        s0 += __shfl_xor(s0, off, 64);
        d0 += __shfl_xor(d0, off, 64);
        s1 += __shfl_xor(s1, off, 64);
        d1 += __shfl_xor(d1, off, 64);
    }
    if (lane == 0) {
        alsrc[n * 2] = s0;  aldst[n * 2] = d0;
        alsrc[n * 2 + 1] = s1;  aldst[n * 2 + 1] = d1;
    }
}

// ---------------- Layer 1 aggregation (chunked lane-parallel online softmax) ----------------

__global__ __launch_bounds__(256) void agg1_k(
        const int* __restrict__ row_start, const int* __restrict__ col,
        const float* __restrict__ xp1, const float* __restrict__ alsrc,
        const float* __restrict__ aldst, const void* __restrict__ b1,
        const int* __restrict__ flags, short* __restrict__ h1b) {
    const int fp32 = flags[0];
    const int wid = threadIdx.x >> 6;
    const int lane = threadIdx.x & 63;
    const int gw = blockIdx.x * 4 + wid;
    const int n = gw >> 1, h = gw & 1;
    __shared__ float2 pbuf[4][64];
    if (n >= N_NODESC) return;
    float2* mybuf = pbuf[wid];
    const float ad = aldst[n * 2 + h];
    float e0 = alsrc[n * 2 + h] + ad;
    e0 = e0 > 0.f ? e0 : 0.2f * e0;
    float m = e0, l = 1.f;
    float acc = xp1[(long)n * 128 + h * 64 + lane];
    const int beg = row_start[n], end = row_start[n + 1];
    for (int base = beg; base < end; base += 64) {
        const int idx = base + lane;
        const int valid = idx < end;
        int s = valid ? col[idx] : 0;
        float e = -3.0e38f;
        if (valid) {
            float t = alsrc[s * 2 + h] + ad;
            e = t > 0.f ? t : 0.2f * t;
        }
        float M = e;
        #pragma unroll
        for (int off = 32; off; off >>= 1) M = fmaxf(M, __shfl_xor(M, off, 64));
        if (M > m) { float sc = __expf(m - M); l *= sc; acc *= sc; m = M; }
        float p = valid ? __expf(e - m) : 0.f;
        float ps = p;
        #pragma unroll
        for (int off = 32; off; off >>= 1) ps += __shfl_xor(ps, off, 64);
        l += ps;
        mybuf[lane] = make_float2(p, __int_as_float(s));
        int cnt = end - base; if (cnt > 64) cnt = 64;
        int j = 0;
        for (; j + 4 <= cnt; j += 4) {
            float2 a0 = mybuf[j], a1 = mybuf[j + 1], a2 = mybuf[j + 2], a3 = mybuf[j + 3];
            float x0 = xp1[(long)__float_as_int(a0.y) * 128 + h * 64 + lane];
            float x1 = xp1[(long)__float_as_int(a1.y) * 128 + h * 64 + lane];
            float x2 = xp1[(long)__float_as_int(a2.y) * 128 + h * 64 + lane];
            float x3 = xp1[(long)__float_as_int(a3.y) * 128 + h * 64 + lane];
            acc = fmaf(a0.x, x0, acc);
            acc = fmaf(a1.x, x1, acc);
            acc = fmaf(a2.x, x2, acc);
            acc = fmaf(a3.x, x3, acc);
        }
        for (; j < cnt; ++j) {
            float2 a = mybuf[j];
            acc = fmaf(a.x, xp1[(long)__float_as_int(a.y) * 128 + h * 64 + lane], acc);
        }
    }
    h1b[(long)n * 128 + h * 64 + lane] = f2s(acc / l + ldf(b1, h * 64 + lane, fp32));
}

// ---------------- Layer 2 GEMM via MFMA: h1[50000,128] @ W2[128,64] ----------------

__global__ __launch_bounds__(256) void gemm2_k(
        const short* __restrict__ h1b, const void* __restrict__ W2,
        const int* __restrict__ flags, float* __restrict__ xp2) {
    const int fp32 = flags[0];
    const int tid = threadIdx.x;
    const int nb = blockIdx.x * 32;
    __shared__ __align__(16) short W2s[8192];       // (c,t,q,n,j) frag-major
    __shared__ __align__(16) short xs[32][136];     // padded rows (2-way banks)

    #pragma unroll
    for (int i = 0; i < 32; ++i) {
        int idx = i * 256 + tid;                    // 8192
        int k = idx >> 6, n = idx & 63;
        float v = ldf(W2, (long)k * 64 + n, fp32);
        int c = n >> 4, nn = n & 15, t = k >> 5, q = (k >> 3) & 3, j = k & 7;
        W2s[(((c * 4 + t) * 4 + q) * 16 + nn) * 8 + j] = f2s(v);
    }
    #pragma unroll
    for (int i = 0; i < 8; ++i) {
        int idx = i * 256 + tid;                    // 2048 ints
        int r = idx >> 6, ii = idx & 63;
        int g = nb + r;
        int val = (g < N_NODESC) ? ((const int*)h1b)[(long)g * 64 + ii] : 0;
        ((int*)&xs[r][0])[ii] = val;
    }
    __syncthreads();

    const int wid = tid >> 6, lane = tid & 63;
    const int quad = lane >> 4, l16 = lane & 15;
    floatx4 acc0 = (floatx4){0.f, 0.f, 0.f, 0.f};
    floatx4 acc1 = (floatx4){0.f, 0.f, 0.f, 0.f};
    #pragma unroll
    for (int t = 0; t < 4; ++t) {
        short8 a0 = *(const short8*)&xs[l16][t * 32 + quad * 8];
        short8 a1 = *(const short8*)&xs[16 + l16][t * 32 + quad * 8];
        short8 b = *(const short8*)&W2s[(((wid * 4 + t) * 4 + quad) * 16 + l16) * 8];
        acc0 = __builtin_amdgcn_mfma_f32_16x16x32_bf16(a0, b, acc0, 0, 0, 0);
        acc1 = __builtin_amdgcn_mfma_f32_16x16x32_bf16(a1, b, acc1, 0, 0, 0);
    }
    const int colg = wid * 16 + l16;
    #pragma unroll
    for (int reg = 0; reg < 4; ++reg) {
        int g0 = nb + quad * 4 + reg;
        int g1 = g0 + 16;
        if (g0 < N_NODESC) xp2[(long)g0 * 64 + colg] = acc0[reg];
        if (g1 < N_NODESC) xp2[(long)g1 * 64 + colg] = acc1[reg];
    }
}

// ---------------- Layer 2 attention logits ----------------

__global__ __launch_bounds__(256) void logits2_k(
        const float* __restrict__ xp2, const void* __restrict__ as2,
        const void* __restrict__ ad2, const int* __restrict__ flags,
        float* __restrict__ alsrc, float* __restrict__ aldst) {
    const int fp32 = flags[0];
    const int wid = threadIdx.x >> 6, lane = threadIdx.x & 63;
    const int n = blockIdx.x * 4 + wid;
    if (n >= N_NODESC) return;
    float v = xp2[(long)n * 64 + lane];
    float s = v * ldf(as2, lane, fp32), d = v * ldf(ad2, lane, fp32);
    #pragma unroll
    for (int off = 32; off; off >>= 1) {
        s += __shfl_xor(s, off, 64);
        d += __shfl_xor(d, off, 64);
    }
    if (lane == 0) { alsrc[n] = s; aldst[n] = d; }
}

// ---------------- Layer 2 aggregation ----------------

__global__ __launch_bounds__(256) void agg2_k(
        const int* __restrict__ row_start, const int* __restrict__ col,
        const float* __restrict__ xp2, const float* __restrict__ alsrc,
        const float* __restrict__ aldst, const void* __restrict__ b2v,
        const int* __restrict__ flags, float* __restrict__ h2) {
    const int fp32 = flags[0];
    const int wid = threadIdx.x >> 6;
    const int lane = threadIdx.x & 63;
    const int n = blockIdx.x * 4 + wid;
    __shared__ float2 pbuf[4][64];
    if (n >= N_NODESC) return;
    float2* mybuf = pbuf[wid];
    const float ad = aldst[n];
    float e0 = alsrc[n] + ad;
    e0 = e0 > 0.f ? e0 : 0.2f * e0;
    float m = e0, l = 1.f;
    float acc = xp2[(long)n * 64 + lane];
    const int beg = row_start[n], end = row_start[n + 1];
    for (int base = beg; base < end; base += 64) {
        const int idx = base + lane;
        const int valid = idx < end;
        int s = valid ? col[idx] : 0;
        float e = -3.0e38f;
        if (valid) {
            float t = alsrc[s] + ad;
            e = t > 0.f ? t : 0.2f * t;
        }
        float M = e;
        #pragma unroll
        for (int off = 32; off; off >>= 1) M = fmaxf(M, __shfl_xor(M, off, 64));
        if (M > m) { float sc = __expf(m - M); l *= sc; acc *= sc; m = M; }
        float p = valid ? __expf(e - m) : 0.f;
        float ps = p;
        #pragma unroll
        for (int off = 32; off; off >>= 1) ps += __shfl_xor(ps, off, 64);
        l += ps;
        mybuf[lane] = make_float2(p, __int_as_float(s));
        int cnt = end - base; if (cnt > 64) cnt = 64;
        int j = 0;
        for (; j + 4 <= cnt; j += 4) {
            float2 a0 = mybuf[j], a1 = mybuf[j + 1], a2 = mybuf[j + 2], a3 = mybuf[j + 3];
            float x0 = xp2[(long)__float_as_int(a0.y) * 64 + lane];
            float x1 = xp2[(long)__float_as_int(a1.y) * 64 + lane];
            float x2 = xp2[(long)__float_as_int(a2.y) * 64 + lane];
            float x3 = xp2[(long)__float_as_int(a3.y) * 64 + lane];
            acc = fmaf(a0.x, x0, acc);
            acc = fmaf(a1.x, x1, acc);
            acc = fmaf(a2.x, x2, acc);
            acc = fmaf(a3.x, x3, acc);
        }
        for (; j < cnt; ++j) {
            float2 a = mybuf[j];
            acc = fmaf(a.x, xp2[(long)__float_as_int(a.y) * 64 + lane], acc);
        }
    }
    h2[(long)n * 64 + lane] = acc / l + ldf(b2v, lane, fp32);
}

// ---------------- mean pool ----------------

__global__ __launch_bounds__(64) void pool_k(const float* __restrict__ h2,
                                             const int* __restrict__ batch,
                                             float* __restrict__ pooled,
                                             float* __restrict__ counts) {
    const int c = threadIdx.x;
    int lo = blockIdx.x * POOL_CHUNK;
    int hi = lo + POOL_CHUNK;
    if (hi > N_NODESC) hi = N_NODESC;
    if (lo >= N_NODESC) return;
    int cur = batch[lo];
    float acc = 0.f;
    int cnt = 0;
    for (int i = lo; i < hi; ++i) {
        int g = batch[i];
        if (g != cur) {
            atomicAdd(&pooled[cur * 64 + c], acc);
            if (c == 0) atomicAdd(&counts[cur], (float)cnt);
            acc = 0.f; cnt = 0; cur = g;
        }
        acc += h2[(long)i * 64 + c];
        cnt++;
    }
    atomicAdd(&pooled[cur * 64 + c], acc);
    if (c == 0) atomicAdd(&counts[cur], (float)cnt);
}

// ---------------- decoder MLP ----------------

__global__ __launch_bounds__(64) void dec_k(const float* __restrict__ pooled,
                                            const float* __restrict__ counts,
                                            const void* __restrict__ Wd1, const void* __restrict__ bd1,
                                            const void* __restrict__ Wd2, const void* __restrict__ bd2,
                                            const int* __restrict__ flags,
                                            void* __restrict__ out) {
    const int fp32 = flags[0];
    const int g = blockIdx.x, j = threadIdx.x;
    __shared__ float p[64], dh[64];
    float cnt = counts[g];
    cnt = cnt < 1.f ? 1.f : cnt;
    p[j] = pooled[g * 64 + j] / cnt;
    __syncthreads();
    float acc = ldf(bd1, j, fp32);
    for (int k = 0; k < 64; ++k) acc += p[k] * ldf(Wd1, k * 64 + j, fp32);
    dh[j] = acc > 0.f ? acc : 0.f;
    __syncthreads();
    if (j < 32) {
        float o = ldf(bd2, j, fp32);
        for (int k = 0; k < 64; ++k) o += dh[k] * ldf(Wd2, k * 32 + j, fp32);
        if (fp32) ((float*)out)[g * 32 + j] = o;
        else      ((bf16*)out)[g * 32 + j] = __float2bfloat16(o);
    }
}

extern "C" void kernel_launch(void* const* d_in, const int* in_sizes, int n_in,
                              void* d_out, int out_size, void* d_ws, size_t ws_size,
                              hipStream_t stream) {
    (void)in_sizes; (void)n_in; (void)out_size; (void)ws_size;
    const void* prot = d_in[0];
    const void* sp   = d_in[1];
    const void* lri  = d_in[2];
    const void* eidx = d_in[3];
    const void* batch= d_in[4];
    const void* W1   = d_in[5];
    const void* as1  = d_in[6];
    const void* ad1  = d_in[7];
    const void* b1   = d_in[8];
    const void* W2   = d_in[9];
    const void* as2  = d_in[10];
    const void* ad2  = d_in[11];
    const void* b2v  = d_in[12];
    const void* Wd1  = d_in[13];
    const void* bd1  = d_in[14];
    const void* Wd2  = d_in[15];
    const void* bd2  = d_in[16];

    char* w = (char*)d_ws;
    auto alloc = [&](size_t bytes) -> void* {
        char* p = w;
        w += (bytes + 255) & ~(size_t)255;
        return (void*)p;
    };
    int*   flags     = (int*)alloc(2 * 4);
    int*   edges32   = (int*)alloc((size_t)2 * N_EDGESC * 4);
    int*   batch32   = (int*)alloc((size_t)N_NODESC * 4);
    int*   deg       = (int*)alloc((size_t)N_NODESC * 4);
    int*   row_start = (int*)alloc((size_t)(N_NODESC + 1) * 4);
    int*   cursor    = (int*)alloc((size_t)N_NODESC * 4);
    int*   col       = (int*)alloc((size_t)N_EDGESC * 4);
    float* xp1       = (float*)alloc((size_t)N_NODESC * 128 * 4);
    float* alsrc1    = (float*)alloc((size_t)N_NODESC * 2 * 4);
    float* aldst1    = (float*)alloc((size_t)N_NODESC * 2 * 4);
    short* h1b       = (short*)alloc((size_t)N_NODESC * 128 * 2);
    float* xp2       = (float*)alloc((size_t)N_NODESC * 64 * 4);
    float* alsrc2    = (float*)alloc((size_t)N_NODESC * 4);
    float* aldst2    = (float*)alloc((size_t)N_NODESC * 4);
    float* h2        = (float*)alloc((size_t)N_NODESC * 64 * 4);
    float* pooled    = (float*)alloc((size_t)NUM_GRAPHSC * 64 * 4);
    float* counts    = (float*)alloc((size_t)NUM_GRAPHSC * 4);

    detect_k<<<1, 64, 0, stream>>>(prot, eidx, flags);
    cvt_edges_k<<<(2 * N_EDGESC + 255) / 256, 256, 0, stream>>>(eidx, edges32, flags);
    cvt_batch_k<<<(N_NODESC + 255) / 256, 256, 0, stream>>>(batch, batch32, flags);
    zero_k<<<(N_NODESC + 255) / 256, 256, 0, stream>>>(deg, N_NODESC);
    zero_k<<<(NUM_GRAPHSC * 64 + 255) / 256, 256, 0, stream>>>((int*)pooled, NUM_GRAPHSC * 64);
    zero_k<<<1, 256, 0, stream>>>((int*)counts, NUM_GRAPHSC);

    const int* srcv = edges32;
    const int* dstv = edges32 + N_EDGESC;

    hist_k<<<(N_EDGESC + 255) / 256, 256, 0, stream>>>(dstv, deg);
    scan_k<<<1, 1024, 0, stream>>>(deg, row_start, cursor);
    scatter_k<<<(N_EDGESC + 255) / 256, 256, 0, stream>>>(srcv, dstv, cursor, col);

    const int nblk = (N_NODESC + 31) / 32;
    gemm1_k<<<nblk, 256, 0, stream>>>(prot, sp, lri, W1, flags, xp1);
    logits1_k<<<(N_NODESC + 3) / 4, 256, 0, stream>>>(xp1, as1, ad1, flags, alsrc1, aldst1);
    agg1_k<<<(2 * N_NODESC + 3) / 4, 256, 0, stream>>>(row_start, col, xp1, alsrc1, aldst1, b1, flags, h1b);
    gemm2_k<<<nblk, 256, 0, stream>>>(h1b, W2, flags, xp2);
    logits2_k<<<(N_NODESC + 3) / 4, 256, 0, stream>>>(xp2, as2, ad2, flags, alsrc2, aldst2);
    agg2_k<<<(N_NODESC + 3) / 4, 256, 0, stream>>>(row_start, col, xp2, alsrc2, aldst2, b2v, flags, h2);
    pool_k<<<(N_NODESC + POOL_CHUNK - 1) / POOL_CHUNK, 64, 0, stream>>>(h2, batch32, pooled, counts);
    dec_k<<<NUM_GRAPHSC, 64, 0, stream>>>(pooled, counts, Wd1, bd1, Wd2, bd2, flags, d_out);
}

// Round 5
// 667.617 us; speedup vs baseline: 1.8672x; 1.1147x over previous
//
#include <hip/hip_runtime.h>
#include <hip/hip_bf16.h>

#define N_NODESC 50000
#define N_EDGESC 1600000
#define IN_DIMC 130
#define NUM_GRAPHSC 64
#define POOL_CHUNK 128
#define SLICE_W 6250          // 50000 / 8
#define EPB 8192              // edges per chunk in sliced scatter

typedef __hip_bfloat16 bf16;
typedef short short8 __attribute__((ext_vector_type(8)));
typedef float floatx4 __attribute__((ext_vector_type(4)));

__device__ __forceinline__ float b2f(bf16 v) { return __bfloat162float(v); }
__device__ __forceinline__ float ldf(const void* p, long i, int fp32) {
    return fp32 ? ((const float*)p)[i] : __bfloat162float(((const bf16*)p)[i]);
}
__device__ __forceinline__ short f2s(float v) {
    bf16 h = __float2bfloat16(v);
    return *(short*)&h;
}
__device__ __forceinline__ float s2f(short u) {
    return __uint_as_float(((unsigned)(unsigned short)u) << 16);
}

// ---------------- dtype detection ----------------
__global__ void detect_k(const void* __restrict__ prot,
                         const void* __restrict__ eidx,
                         int* __restrict__ flags) {
    if (blockIdx.x == 0 && threadIdx.x == 0) {
        const bf16* pb = (const bf16*)prot;
        int sane = 0;
        for (int i = 0; i < 64; ++i) {
            float a = fabsf(__bfloat162float(pb[2 * i]));
            if (a > 1e-8f && a < 1e4f) sane++;
        }
        flags[0] = (sane >= 48) ? 0 : 1;
        const unsigned* u = (const unsigned*)eidx;
        int zhi = 0;
        for (int i = 0; i < 32; ++i)
            if (u[2 * i + 1] == 0u) zhi++;
        flags[1] = (zhi >= 30) ? 1 : 0;
    }
}

// fused: int64->int32 edge convert + dst histogram
__global__ __launch_bounds__(256) void cvt_hist_k(const void* __restrict__ eidx,
                                                  int* __restrict__ edges32,
                                                  int* __restrict__ deg,
                                                  const int* __restrict__ flags) {
    const int i64f = flags[1];
    int e = blockIdx.x * 256 + threadIdx.x;
    if (e < N_EDGESC) {
        int s, d;
        if (i64f) {
            s = (int)((const long long*)eidx)[e];
            d = (int)((const long long*)eidx)[N_EDGESC + e];
        } else {
            s = ((const int*)eidx)[e];
            d = ((const int*)eidx)[N_EDGESC + e];
        }
        edges32[e] = s;
        edges32[N_EDGESC + e] = d;
        atomicAdd(&deg[d], 1);
    }
}

__global__ __launch_bounds__(256) void cvt_batch_k(const void* __restrict__ b,
                                                   int* __restrict__ b32,
                                                   const int* __restrict__ flags) {
    const int i64f = flags[1];
    int i = blockIdx.x * 256 + threadIdx.x;
    if (i < N_NODESC)
        b32[i] = i64f ? (int)((const long long*)b)[i] : ((const int*)b)[i];
}

__global__ __launch_bounds__(256) void zero_k(int* __restrict__ p, int n) {
    int i = blockIdx.x * 256 + threadIdx.x;
    if (i < n) p[i] = 0;
}

__global__ __launch_bounds__(1024) void scan_k(const int* __restrict__ deg,
                                               int* __restrict__ row_start,
                                               int* __restrict__ cursor) {
    __shared__ int sums[1024];
    const int tid = threadIdx.x;
    const int CH = (N_NODESC + 1023) / 1024;
    int lo = tid * CH;
    int hi = lo + CH;
    if (hi > N_NODESC) hi = N_NODESC;
    if (lo > N_NODESC) lo = N_NODESC;
    int s = 0;
    for (int i = lo; i < hi; ++i) s += deg[i];
    sums[tid] = s;
    __syncthreads();
    for (int off = 1; off < 1024; off <<= 1) {
        int t = (tid >= off) ? sums[tid - off] : 0;
        __syncthreads();
        sums[tid] += t;
        __syncthreads();
    }
    int run = sums[tid] - s;
    for (int i = lo; i < hi; ++i) {
        row_start[i] = run;
        cursor[i] = run;
        run += deg[i];
    }
    if (tid == 1023) row_start[N_NODESC] = sums[1023];
}

// XCD-sliced scatter: block b handles dst slice (b&7) over edge chunk (b>>3).
// CSR col range for a slice is contiguous -> each 64B line written by one XCD.
__global__ __launch_bounds__(256) void scatter_k(const int* __restrict__ srcv,
                                                 const int* __restrict__ dstv,
                                                 int* __restrict__ cursor,
                                                 int* __restrict__ col) {
    const int slice = blockIdx.x & 7;
    const int chunk = blockIdx.x >> 3;
    const int lo = slice * SLICE_W, hi = lo + SLICE_W;
    int e = chunk * EPB + threadIdx.x;
    int eend = (chunk + 1) * EPB;
    if (eend > N_EDGESC) eend = N_EDGESC;
    for (; e < eend; e += 256) {
        int d = dstv[e];
        if (d >= lo && d < hi) {
            int pos = atomicAdd(&cursor[d], 1);
            col[pos] = srcv[e];
        }
    }
}

// ---------------- Layer 1 GEMM via MFMA: x[50000,130] @ W1[130,128] ----------------

__global__ __launch_bounds__(256) void gemm1_k(
        const void* __restrict__ prot, const void* __restrict__ sp,
        const void* __restrict__ lri,  const void* __restrict__ W1,
        const int* __restrict__ flags, float* __restrict__ xp1,
        short* __restrict__ xp1b) {
    const int fp32 = flags[0];
    const int tid = threadIdx.x;
    const int nb = blockIdx.x * 32;
    __shared__ __align__(16) short W1s[16384];
    __shared__ float W1r[2][128];
    __shared__ __align__(16) short xs[32][136];
    __shared__ float xsp[32][2];

    #pragma unroll
    for (int i = 0; i < 64; ++i) {
        int idx = i * 256 + tid;
        int k = idx >> 7, n = idx & 127;
        float v = ldf(W1, (long)k * 128 + n, fp32);
        int c = n >> 4, nn = n & 15, t = k >> 5, q = (k >> 3) & 3, j = k & 7;
        W1s[(((c * 4 + t) * 4 + q) * 16 + nn) * 8 + j] = f2s(v);
    }
    W1r[tid >> 7][tid & 127] = ldf(W1, (long)(128 + (tid >> 7)) * 128 + (tid & 127), fp32);
    #pragma unroll
    for (int i = 0; i < 16; ++i) {
        int idx = i * 256 + tid;
        int r = idx >> 7, k = idx & 127;
        int g = nb + r;
        float v = 0.f;
        if (g < N_NODESC) {
            if (k < 64)      v = ldf(prot, (long)g * 64 + k, fp32);
            else if (k < 66) v = ldf(sp, (long)g * 2 + (k - 64), fp32);
            else             v = ldf(lri, (long)g * 64 + (k - 66), fp32);
        }
        xs[r][k] = f2s(v);
    }
    if (tid < 64) {
        int r = tid >> 1, which = tid & 1;
        int g = nb + r;
        xsp[r][which] = (g < N_NODESC) ? ldf(lri, (long)g * 64 + 62 + which, fp32) : 0.f;
    }
    __syncthreads();

    const int wid = tid >> 6, lane = tid & 63;
    const int quad = lane >> 4, l16 = lane & 15;
    floatx4 acc[2][2];
    #pragma unroll
    for (int a = 0; a < 2; ++a)
        #pragma unroll
        for (int b = 0; b < 2; ++b) acc[a][b] = (floatx4){0.f, 0.f, 0.f, 0.f};

    const int c0 = 2 * wid;
    #pragma unroll
    for (int t = 0; t < 4; ++t) {
        short8 a0 = *(const short8*)&xs[l16][t * 32 + quad * 8];
        short8 a1 = *(const short8*)&xs[16 + l16][t * 32 + quad * 8];
        short8 b0 = *(const short8*)&W1s[(((c0 * 4 + t) * 4 + quad) * 16 + l16) * 8];
        short8 b1 = *(const short8*)&W1s[((((c0 + 1) * 4 + t) * 4 + quad) * 16 + l16) * 8];
        acc[0][0] = __builtin_amdgcn_mfma_f32_16x16x32_bf16(a0, b0, acc[0][0], 0, 0, 0);
        acc[0][1] = __builtin_amdgcn_mfma_f32_16x16x32_bf16(a0, b1, acc[0][1], 0, 0, 0);
        acc[1][0] = __builtin_amdgcn_mfma_f32_16x16x32_bf16(a1, b0, acc[1][0], 0, 0, 0);
        acc[1][1] = __builtin_amdgcn_mfma_f32_16x16x32_bf16(a1, b1, acc[1][1], 0, 0, 0);
    }
    #pragma unroll
    for (int rt = 0; rt < 2; ++rt) {
        #pragma unroll
        for (int ci = 0; ci < 2; ++ci) {
            int colg = (c0 + ci) * 16 + l16;
            float w0 = W1r[0][colg], w1 = W1r[1][colg];
            #pragma unroll
            for (int reg = 0; reg < 4; ++reg) {
                int row = rt * 16 + quad * 4 + reg;
                int g = nb + row;
                if (g < N_NODESC) {
                    float v = acc[rt][ci][reg] + xsp[row][0] * w0 + xsp[row][1] * w1;
                    xp1[(long)g * 128 + colg] = v;
                    xp1b[(long)g * 128 + colg] = f2s(v);
                }
            }
        }
    }
}

// ---------------- Layer 1 attention logits ----------------

__global__ __launch_bounds__(256) void logits1_k(
        const float* __restrict__ xp1, const void* __restrict__ as1,
        const void* __restrict__ ad1, const int* __restrict__ flags,
        float* __restrict__ alsrc, float* __restrict__ aldst) {
    const int fp32 = flags[0];
    const int wid = threadIdx.x >> 6, lane = threadIdx.x & 63;
    const int n = blockIdx.x * 4 + wid;
    if (n >= N_NODESC) return;
    float v0 = xp1[(long)n * 128 + lane];
    float v1 = xp1[(long)n * 128 + 64 + lane];
    float s0 = v0 * ldf(as1, lane, fp32), d0 = v0 * ldf(ad1, lane, fp32);
    float s1 = v1 * ldf(as1, 64 + lane, fp32), d1 = v1 * ldf(ad1, 64 + lane, fp32);
    #pragma unroll
    for (int off = 32; off; off >>= 1) {
        s0 += __shfl_xor(s0, off, 64);
        d0 += __shfl_xor(d0, off, 64);
        s1 += __shfl_xor(s1, off, 64);
        d1 += __shfl_xor(d1, off, 64);
    }
    if (lane == 0) {
        alsrc[n * 2] = s0;  aldst[n * 2] = d0;
        alsrc[n * 2 + 1] = s1;  aldst[n * 2 + 1] = d1;
    }
}

// ---------------- Layer 1 aggregation (bf16 gather) ----------------

__global__ __launch_bounds__(256) void agg1_k(
        const int* __restrict__ row_start, const int* __restrict__ col,
        const short* __restrict__ xp1b, const float* __restrict__ alsrc,
        const float* __restrict__ aldst, const void* __restrict__ b1,
        const int* __restrict__ flags, short* __restrict__ h1b) {
    const int fp32 = flags[0];
    const int wid = threadIdx.x >> 6;
    const int lane = threadIdx.x & 63;
    const int gw = blockIdx.x * 4 + wid;
    const int n = gw >> 1, h = gw & 1;
    __shared__ float2 pbuf[4][64];
    if (n >= N_NODESC) return;
    float2* mybuf = pbuf[wid];
    const float ad = aldst[n * 2 + h];
    float e0 = alsrc[n * 2 + h] + ad;
    e0 = e0 > 0.f ? e0 : 0.2f * e0;
    float m = e0, l = 1.f;
    float acc = s2f(xp1b[(long)n * 128 + h * 64 + lane]);
    const int beg = row_start[n], end = row_start[n + 1];
    for (int base = beg; base < end; base += 64) {
        const int idx = base + lane;
        const int valid = idx < end;
        int s = valid ? col[idx] : 0;
        float e = -3.0e38f;
        if (valid) {
            float t = alsrc[s * 2 + h] + ad;
            e = t > 0.f ? t : 0.2f * t;
        }
        float M = e;
        #pragma unroll
        for (int off = 32; off; off >>= 1) M = fmaxf(M, __shfl_xor(M, off, 64));
        if (M > m) { float sc = __expf(m - M); l *= sc; acc *= sc; m = M; }
        float p = valid ? __expf(e - m) : 0.f;
        float ps = p;
        #pragma unroll
        for (int off = 32; off; off >>= 1) ps += __shfl_xor(ps, off, 64);
        l += ps;
        mybuf[lane] = make_float2(p, __int_as_float(s));
        int cnt = end - base; if (cnt > 64) cnt = 64;
        int j = 0;
        for (; j + 4 <= cnt; j += 4) {
            float2 a0 = mybuf[j], a1 = mybuf[j + 1], a2 = mybuf[j + 2], a3 = mybuf[j + 3];
            float x0 = s2f(xp1b[(long)__float_as_int(a0.y) * 128 + h * 64 + lane]);
            float x1 = s2f(xp1b[(long)__float_as_int(a1.y) * 128 + h * 64 + lane]);
            float x2 = s2f(xp1b[(long)__float_as_int(a2.y) * 128 + h * 64 + lane]);
            float x3 = s2f(xp1b[(long)__float_as_int(a3.y) * 128 + h * 64 + lane]);
            acc = fmaf(a0.x, x0, acc);
            acc = fmaf(a1.x, x1, acc);
            acc = fmaf(a2.x, x2, acc);
            acc = fmaf(a3.x, x3, acc);
        }
        for (; j < cnt; ++j) {
            float2 a = mybuf[j];
            acc = fmaf(a.x, s2f(xp1b[(long)__float_as_int(a.y) * 128 + h * 64 + lane]), acc);
        }
    }
    h1b[(long)n * 128 + h * 64 + lane] = f2s(acc / l + ldf(b1, h * 64 + lane, fp32));
}

// ---------------- Layer 2 GEMM via MFMA: h1[50000,128] @ W2[128,64] ----------------

__global__ __launch_bounds__(256) void gemm2_k(
        const short* __restrict__ h1b, const void* __restrict__ W2,
        const int* __restrict__ flags, float* __restrict__ xp2,
        short* __restrict__ xp2b) {
    const int fp32 = flags[0];
    const int tid = threadIdx.x;
    const int nb = blockIdx.x * 32;
    __shared__ __align__(16) short W2s[8192];
    __shared__ __align__(16) short xs[32][136];

    #pragma unroll
    for (int i = 0; i < 32; ++i) {
        int idx = i * 256 + tid;
        int k = idx >> 6, n = idx & 63;
        float v = ldf(W2, (long)k * 64 + n, fp32);
        int c = n >> 4, nn = n & 15, t = k >> 5, q = (k >> 3) & 3, j = k & 7;
        W2s[(((c * 4 + t) * 4 + q) * 16 + nn) * 8 + j] = f2s(v);
    }
    #pragma unroll
    for (int i = 0; i < 8; ++i) {
        int idx = i * 256 + tid;
        int r = idx >> 6, ii = idx & 63;
        int g = nb + r;
        int val = (g < N_NODESC) ? ((const int*)h1b)[(long)g * 64 + ii] : 0;
        ((int*)&xs[r][0])[ii] = val;
    }
    __syncthreads();

    const int wid = tid >> 6, lane = tid & 63;
    const int quad = lane >> 4, l16 = lane & 15;
    floatx4 acc0 = (floatx4){0.f, 0.f, 0.f, 0.f};
    floatx4 acc1 = (floatx4){0.f, 0.f, 0.f, 0.f};
    #pragma unroll
    for (int t = 0; t < 4; ++t) {
        short8 a0 = *(const short8*)&xs[l16][t * 32 + quad * 8];
        short8 a1 = *(const short8*)&xs[16 + l16][t * 32 + quad * 8];
        short8 b = *(const short8*)&W2s[(((wid * 4 + t) * 4 + quad) * 16 + l16) * 8];
        acc0 = __builtin_amdgcn_mfma_f32_16x16x32_bf16(a0, b, acc0, 0, 0, 0);
        acc1 = __builtin_amdgcn_mfma_f32_16x16x32_bf16(a1, b, acc1, 0, 0, 0);
    }
    const int colg = wid * 16 + l16;
    #pragma unroll
    for (int reg = 0; reg < 4; ++reg) {
        int g0 = nb + quad * 4 + reg;
        int g1 = g0 + 16;
        if (g0 < N_NODESC) {
            xp2[(long)g0 * 64 + colg] = acc0[reg];
            xp2b[(long)g0 * 64 + colg] = f2s(acc0[reg]);
        }
        if (g1 < N_NODESC) {
            xp2[(long)g1 * 64 + colg] = acc1[reg];
            xp2b[(long)g1 * 64 + colg] = f2s(acc1[reg]);
        }
    }
}

// ---------------- Layer 2 attention logits ----------------

__global__ __launch_bounds__(256) void logits2_k(
        const float* __restrict__ xp2, const void* __restrict__ as2,
        const void* __restrict__ ad2, const int* __restrict__ flags,
        float* __restrict__ alsrc, float* __restrict__ aldst) {
    const int fp32 = flags[0];
    const int wid = threadIdx.x >> 6, lane = threadIdx.x & 63;
    const int n = blockIdx.x * 4 + wid;
    if (n >= N_NODESC) return;
    float v = xp2[(long)n * 64 + lane];
    float s = v * ldf(as2, lane, fp32), d = v * ldf(ad2, lane, fp32);
    #pragma unroll
    for (int off = 32; off; off >>= 1) {
        s += __shfl_xor(s, off, 64);
        d += __shfl_xor(d, off, 64);
    }
    if (lane == 0) { alsrc[n] = s; aldst[n] = d; }
}

// ---------------- Layer 2 aggregation (bf16 gather) ----------------

__global__ __launch_bounds__(256) void agg2_k(
        const int* __restrict__ row_start, const int* __restrict__ col,
        const short* __restrict__ xp2b, const float* __restrict__ alsrc,
        const float* __restrict__ aldst, const void* __restrict__ b2v,
        const int* __restrict__ flags, float* __restrict__ h2) {
    const int fp32 = flags[0];
    const int wid = threadIdx.x >> 6;
    const int lane = threadIdx.x & 63;
    const int n = blockIdx.x * 4 + wid;
    __shared__ float2 pbuf[4][64];
    if (n >= N_NODESC) return;
    float2* mybuf = pbuf[wid];
    const float ad = aldst[n];
    float e0 = alsrc[n] + ad;
    e0 = e0 > 0.f ? e0 : 0.2f * e0;
    float m = e0, l = 1.f;
    float acc = s2f(xp2b[(long)n * 64 + lane]);
    const int beg = row_start[n], end = row_start[n + 1];
    for (int base = beg; base < end; base += 64) {
        const int idx = base + lane;
        const int valid = idx < end;
        int s = valid ? col[idx] : 0;
        float e = -3.0e38f;
        if (valid) {
            float t = alsrc[s] + ad;
            e = t > 0.f ? t : 0.2f * t;
        }
        float M = e;
        #pragma unroll
        for (int off = 32; off; off >>= 1) M = fmaxf(M, __shfl_xor(M, off, 64));
        if (M > m) { float sc = __expf(m - M); l *= sc; acc *= sc; m = M; }
        float p = valid ? __expf(e - m) : 0.f;
        float ps = p;
        #pragma unroll
        for (int off = 32; off; off >>= 1) ps += __shfl_xor(ps, off, 64);
        l += ps;
        mybuf[lane] = make_float2(p, __int_as_float(s));
        int cnt = end - base; if (cnt > 64) cnt = 64;
        int j = 0;
        for (; j + 4 <= cnt; j += 4) {
            float2 a0 = mybuf[j], a1 = mybuf[j + 1], a2 = mybuf[j + 2], a3 = mybuf[j + 3];
            float x0 = s2f(xp2b[(long)__float_as_int(a0.y) * 64 + lane]);
            float x1 = s2f(xp2b[(long)__float_as_int(a1.y) * 64 + lane]);
            float x2 = s2f(xp2b[(long)__float_as_int(a2.y) * 64 + lane]);
            float x3 = s2f(xp2b[(long)__float_as_int(a3.y) * 64 + lane]);
            acc = fmaf(a0.x, x0, acc);
            acc = fmaf(a1.x, x1, acc);
            acc = fmaf(a2.x, x2, acc);
            acc = fmaf(a3.x, x3, acc);
        }
        for (; j < cnt; ++j) {
            float2 a = mybuf[j];
            acc = fmaf(a.x, s2f(xp2b[(long)__float_as_int(a.y) * 64 + lane]), acc);
        }
    }
    h2[(long)n * 64 + lane] = acc / l + ldf(b2v, lane, fp32);
}

// ---------------- mean pool ----------------

__global__ __launch_bounds__(64) void pool_k(const float* __restrict__ h2,
                                             const int* __restrict__ batch,
                                             float* __restrict__ pooled,
                                             float* __restrict__ counts) {
    const int c = threadIdx.x;
    int lo = blockIdx.x * POOL_CHUNK;
    int hi = lo + POOL_CHUNK;
    if (hi > N_NODESC) hi = N_NODESC;
    if (lo >= N_NODESC) return;
    int cur = batch[lo];
    float acc = 0.f;
    int cnt = 0;
    for (int i = lo; i < hi; ++i) {
        int g = batch[i];
        if (g != cur) {
            atomicAdd(&pooled[cur * 64 + c], acc);
            if (c == 0) atomicAdd(&counts[cur], (float)cnt);
            acc = 0.f; cnt = 0; cur = g;
        }
        acc += h2[(long)i * 64 + c];
        cnt++;
    }
    atomicAdd(&pooled[cur * 64 + c], acc);
    if (c == 0) atomicAdd(&counts[cur], (float)cnt);
}

// ---------------- decoder MLP ----------------

__global__ __launch_bounds__(64) void dec_k(const float* __restrict__ pooled,
                                            const float* __restrict__ counts,
                                            const void* __restrict__ Wd1, const void* __restrict__ bd1,
                                            const void* __restrict__ Wd2, const void* __restrict__ bd2,
                                            const int* __restrict__ flags,
                                            void* __restrict__ out) {
    const int fp32 = flags[0];
    const int g = blockIdx.x, j = threadIdx.x;
    __shared__ float p[64], dh[64];
    float cnt = counts[g];
    cnt = cnt < 1.f ? 1.f : cnt;
    p[j] = pooled[g * 64 + j] / cnt;
    __syncthreads();
    float acc = ldf(bd1, j, fp32);
    for (int k = 0; k < 64; ++k) acc += p[k] * ldf(Wd1, k * 64 + j, fp32);
    dh[j] = acc > 0.f ? acc : 0.f;
    __syncthreads();
    if (j < 32) {
        float o = ldf(bd2, j, fp32);
        for (int k = 0; k < 64; ++k) o += dh[k] * ldf(Wd2, k * 32 + j, fp32);
        if (fp32) ((float*)out)[g * 32 + j] = o;
        else      ((bf16*)out)[g * 32 + j] = __float2bfloat16(o);
    }
}

extern "C" void kernel_launch(void* const* d_in, const int* in_sizes, int n_in,
                              void* d_out, int out_size, void* d_ws, size_t ws_size,
                              hipStream_t stream) {
    (void)in_sizes; (void)n_in; (void)out_size; (void)ws_size;
    const void* prot = d_in[0];
    const void* sp   = d_in[1];
    const void* lri  = d_in[2];
    const void* eidx = d_in[3];
    const void* batch= d_in[4];
    const void* W1   = d_in[5];
    const void* as1  = d_in[6];
    const void* ad1  = d_in[7];
    const void* b1   = d_in[8];
    const void* W2   = d_in[9];
    const void* as2  = d_in[10];
    const void* ad2  = d_in[11];
    const void* b2v  = d_in[12];
    const void* Wd1  = d_in[13];
    const void* bd1  = d_in[14];
    const void* Wd2  = d_in[15];
    const void* bd2  = d_in[16];

    char* w = (char*)d_ws;
    auto alloc = [&](size_t bytes) -> void* {
        char* p = w;
        w += (bytes + 255) & ~(size_t)255;
        return (void*)p;
    };
    int*   flags     = (int*)alloc(2 * 4);
    int*   edges32   = (int*)alloc((size_t)2 * N_EDGESC * 4);
    int*   batch32   = (int*)alloc((size_t)N_NODESC * 4);
    int*   deg       = (int*)alloc((size_t)N_NODESC * 4);
    int*   row_start = (int*)alloc((size_t)(N_NODESC + 1) * 4);
    int*   cursor    = (int*)alloc((size_t)N_NODESC * 4);
    int*   col       = (int*)alloc((size_t)N_EDGESC * 4);
    float* xp1       = (float*)alloc((size_t)N_NODESC * 128 * 4);
    short* xp1b      = (short*)alloc((size_t)N_NODESC * 128 * 2);
    float* alsrc1    = (float*)alloc((size_t)N_NODESC * 2 * 4);
    float* aldst1    = (float*)alloc((size_t)N_NODESC * 2 * 4);
    short* h1b       = (short*)alloc((size_t)N_NODESC * 128 * 2);
    float* xp2       = (float*)alloc((size_t)N_NODESC * 64 * 4);
    short* xp2b      = (short*)alloc((size_t)N_NODESC * 64 * 2);
    float* alsrc2    = (float*)alloc((size_t)N_NODESC * 4);
    float* aldst2    = (float*)alloc((size_t)N_NODESC * 4);
    float* h2        = (float*)alloc((size_t)N_NODESC * 64 * 4);
    float* pooled    = (float*)alloc((size_t)NUM_GRAPHSC * 64 * 4);
    float* counts    = (float*)alloc((size_t)NUM_GRAPHSC * 4);

    detect_k<<<1, 64, 0, stream>>>(prot, eidx, flags);
    zero_k<<<(N_NODESC + 255) / 256, 256, 0, stream>>>(deg, N_NODESC);
    zero_k<<<(NUM_GRAPHSC * 64 + 255) / 256, 256, 0, stream>>>((int*)pooled, NUM_GRAPHSC * 64);
    zero_k<<<1, 256, 0, stream>>>((int*)counts, NUM_GRAPHSC);
    cvt_hist_k<<<(N_EDGESC + 255) / 256, 256, 0, stream>>>(eidx, edges32, deg, flags);
    cvt_batch_k<<<(N_NODESC + 255) / 256, 256, 0, stream>>>(batch, batch32, flags);

    const int* srcv = edges32;
    const int* dstv = edges32 + N_EDGESC;

    scan_k<<<1, 1024, 0, stream>>>(deg, row_start, cursor);
    {
        const int nchunk = (N_EDGESC + EPB - 1) / EPB;
        scatter_k<<<nchunk * 8, 256, 0, stream>>>(srcv, dstv, cursor, col);
    }

    const int nblk = (N_NODESC + 31) / 32;
    gemm1_k<<<nblk, 256, 0, stream>>>(prot, sp, lri, W1, flags, xp1, xp1b);
    logits1_k<<<(N_NODESC + 3) / 4, 256, 0, stream>>>(xp1, as1, ad1, flags, alsrc1, aldst1);
    agg1_k<<<(2 * N_NODESC + 3) / 4, 256, 0, stream>>>(row_start, col, xp1b, alsrc1, aldst1, b1, flags, h1b);
    gemm2_k<<<nblk, 256, 0, stream>>>(h1b, W2, flags, xp2, xp2b);
    logits2_k<<<(N_NODESC + 3) / 4, 256, 0, stream>>>(xp2, as2, ad2, flags, alsrc2, aldst2);
    agg2_k<<<(N_NODESC + 3) / 4, 256, 0, stream>>>(row_start, col, xp2b, alsrc2, aldst2, b2v, flags, h2);
    pool_k<<<(N_NODESC + POOL_CHUNK - 1) / POOL_CHUNK, 64, 0, stream>>>(h2, batch32, pooled, counts);
    dec_k<<<NUM_GRAPHSC, 64, 0, stream>>>(pooled, counts, Wd1, bd1, Wd2, bd2, flags, d_out);
}

// Round 6
// 572.095 us; speedup vs baseline: 2.1790x; 1.1670x over previous
//
#include <hip/hip_runtime.h>
#include <hip/hip_bf16.h>

#define N_NODESC 50000
#define N_EDGESC 1600000
#define IN_DIMC 130
#define NUM_GRAPHSC 64
#define POOL_CHUNK 128
#define SLICE_W 6250          // 50000 / 8
#define EPB 8192              // edges per chunk in sliced scatter
#define SCAN_B 256
#define SCAN_NB ((N_NODESC + SCAN_B - 1) / SCAN_B)   // 196

typedef __hip_bfloat16 bf16;
typedef short short8 __attribute__((ext_vector_type(8)));
typedef float floatx4 __attribute__((ext_vector_type(4)));

__device__ __forceinline__ float b2f(bf16 v) { return __bfloat162float(v); }
__device__ __forceinline__ float ldf(const void* p, long i, int fp32) {
    return fp32 ? ((const float*)p)[i] : __bfloat162float(((const bf16*)p)[i]);
}
__device__ __forceinline__ short f2s(float v) {
    bf16 h = __float2bfloat16(v);
    return *(short*)&h;
}
__device__ __forceinline__ float s2f(short u) {
    return __uint_as_float(((unsigned)(unsigned short)u) << 16);
}

// ---------------- dtype detection ----------------
__global__ void detect_k(const void* __restrict__ prot,
                         const void* __restrict__ eidx,
                         int* __restrict__ flags) {
    if (blockIdx.x == 0 && threadIdx.x == 0) {
        const bf16* pb = (const bf16*)prot;
        int sane = 0;
        for (int i = 0; i < 64; ++i) {
            float a = fabsf(__bfloat162float(pb[2 * i]));
            if (a > 1e-8f && a < 1e4f) sane++;
        }
        flags[0] = (sane >= 48) ? 0 : 1;
        const unsigned* u = (const unsigned*)eidx;
        int zhi = 0;
        for (int i = 0; i < 32; ++i)
            if (u[2 * i + 1] == 0u) zhi++;
        flags[1] = (zhi >= 30) ? 1 : 0;
    }
}

// fused: int64->int32 edge convert + dst histogram
__global__ __launch_bounds__(256) void cvt_hist_k(const void* __restrict__ eidx,
                                                  int* __restrict__ edges32,
                                                  int* __restrict__ deg,
                                                  const int* __restrict__ flags) {
    const int i64f = flags[1];
    int e = blockIdx.x * 256 + threadIdx.x;
    if (e < N_EDGESC) {
        int s, d;
        if (i64f) {
            s = (int)((const long long*)eidx)[e];
            d = (int)((const long long*)eidx)[N_EDGESC + e];
        } else {
            s = ((const int*)eidx)[e];
            d = ((const int*)eidx)[N_EDGESC + e];
        }
        edges32[e] = s;
        edges32[N_EDGESC + e] = d;
        atomicAdd(&deg[d], 1);
    }
}

__global__ __launch_bounds__(256) void cvt_batch_k(const void* __restrict__ b,
                                                   int* __restrict__ b32,
                                                   const int* __restrict__ flags) {
    const int i64f = flags[1];
    int i = blockIdx.x * 256 + threadIdx.x;
    if (i < N_NODESC)
        b32[i] = i64f ? (int)((const long long*)b)[i] : ((const int*)b)[i];
}

__global__ __launch_bounds__(256) void zero_k(int* __restrict__ p, int n) {
    int i = blockIdx.x * 256 + threadIdx.x;
    if (i < n) p[i] = 0;
}

// ---------------- multi-block exclusive scan of deg ----------------

__global__ __launch_bounds__(SCAN_B) void partial_k(const int* __restrict__ deg,
                                                    int* __restrict__ blocksum) {
    const int tid = threadIdx.x;
    const int i = blockIdx.x * SCAN_B + tid;
    int v = (i < N_NODESC) ? deg[i] : 0;
    #pragma unroll
    for (int off = 32; off; off >>= 1) v += __shfl_xor(v, off, 64);
    __shared__ int ws[4];
    if ((tid & 63) == 0) ws[tid >> 6] = v;
    __syncthreads();
    if (tid == 0) blocksum[blockIdx.x] = ws[0] + ws[1] + ws[2] + ws[3];
}

__global__ __launch_bounds__(SCAN_B) void scanpart_k(int* __restrict__ blocksum,
                                                     int* __restrict__ blockoff) {
    __shared__ int s[SCAN_B];
    const int tid = threadIdx.x;
    int v = (tid < SCAN_NB) ? blocksum[tid] : 0;
    s[tid] = v;
    __syncthreads();
    for (int off = 1; off < SCAN_B; off <<= 1) {
        int t = (tid >= off) ? s[tid - off] : 0;
        __syncthreads();
        s[tid] += t;
        __syncthreads();
    }
    if (tid < SCAN_NB) blockoff[tid] = s[tid] - v;   // exclusive
}

__global__ __launch_bounds__(SCAN_B) void scanwrite_k(const int* __restrict__ deg,
                                                      const int* __restrict__ blockoff,
                                                      int* __restrict__ row_start,
                                                      int* __restrict__ cursor) {
    __shared__ int s[SCAN_B];
    const int tid = threadIdx.x;
    const int i = blockIdx.x * SCAN_B + tid;
    int d = (i < N_NODESC) ? deg[i] : 0;
    s[tid] = d;
    __syncthreads();
    for (int off = 1; off < SCAN_B; off <<= 1) {
        int t = (tid >= off) ? s[tid - off] : 0;
        __syncthreads();
        s[tid] += t;
        __syncthreads();
    }
    int excl = s[tid] - d + blockoff[blockIdx.x];
    if (i < N_NODESC) {
        row_start[i] = excl;
        cursor[i] = excl;
        if (i == N_NODESC - 1) row_start[N_NODESC] = excl + d;
    }
}

// XCD-sliced scatter: block b handles dst slice (b&7) over edge chunk (b>>3).
__global__ __launch_bounds__(256) void scatter_k(const int* __restrict__ srcv,
                                                 const int* __restrict__ dstv,
                                                 int* __restrict__ cursor,
                                                 int* __restrict__ col) {
    const int slice = blockIdx.x & 7;
    const int chunk = blockIdx.x >> 3;
    const int lo = slice * SLICE_W, hi = lo + SLICE_W;
    int e = chunk * EPB + threadIdx.x;
    int eend = (chunk + 1) * EPB;
    if (eend > N_EDGESC) eend = N_EDGESC;
    for (; e < eend; e += 256) {
        int d = dstv[e];
        if (d >= lo && d < hi) {
            int pos = atomicAdd(&cursor[d], 1);
            col[pos] = srcv[e];
        }
    }
}

// ---------------- Layer 1 GEMM via MFMA: x[50000,130] @ W1[130,128] ----------------

__global__ __launch_bounds__(256) void gemm1_k(
        const void* __restrict__ prot, const void* __restrict__ sp,
        const void* __restrict__ lri,  const void* __restrict__ W1,
        const int* __restrict__ flags, float* __restrict__ xp1,
        short* __restrict__ xp1b) {
    const int fp32 = flags[0];
    const int tid = threadIdx.x;
    const int nb = blockIdx.x * 32;
    __shared__ __align__(16) short W1s[16384];
    __shared__ float W1r[2][128];
    __shared__ __align__(16) short xs[32][136];
    __shared__ float xsp[32][2];

    #pragma unroll
    for (int i = 0; i < 64; ++i) {
        int idx = i * 256 + tid;
        int k = idx >> 7, n = idx & 127;
        float v = ldf(W1, (long)k * 128 + n, fp32);
        int c = n >> 4, nn = n & 15, t = k >> 5, q = (k >> 3) & 3, j = k & 7;
        W1s[(((c * 4 + t) * 4 + q) * 16 + nn) * 8 + j] = f2s(v);
    }
    W1r[tid >> 7][tid & 127] = ldf(W1, (long)(128 + (tid >> 7)) * 128 + (tid & 127), fp32);
    #pragma unroll
    for (int i = 0; i < 16; ++i) {
        int idx = i * 256 + tid;
        int r = idx >> 7, k = idx & 127;
        int g = nb + r;
        float v = 0.f;
        if (g < N_NODESC) {
            if (k < 64)      v = ldf(prot, (long)g * 64 + k, fp32);
            else if (k < 66) v = ldf(sp, (long)g * 2 + (k - 64), fp32);
            else             v = ldf(lri, (long)g * 64 + (k - 66), fp32);
        }
        xs[r][k] = f2s(v);
    }
    if (tid < 64) {
        int r = tid >> 1, which = tid & 1;
        int g = nb + r;
        xsp[r][which] = (g < N_NODESC) ? ldf(lri, (long)g * 64 + 62 + which, fp32) : 0.f;
    }
    __syncthreads();

    const int wid = tid >> 6, lane = tid & 63;
    const int quad = lane >> 4, l16 = lane & 15;
    floatx4 acc[2][2];
    #pragma unroll
    for (int a = 0; a < 2; ++a)
        #pragma unroll
        for (int b = 0; b < 2; ++b) acc[a][b] = (floatx4){0.f, 0.f, 0.f, 0.f};

    const int c0 = 2 * wid;
    #pragma unroll
    for (int t = 0; t < 4; ++t) {
        short8 a0 = *(const short8*)&xs[l16][t * 32 + quad * 8];
        short8 a1 = *(const short8*)&xs[16 + l16][t * 32 + quad * 8];
        short8 b0 = *(const short8*)&W1s[(((c0 * 4 + t) * 4 + quad) * 16 + l16) * 8];
        short8 b1 = *(const short8*)&W1s[((((c0 + 1) * 4 + t) * 4 + quad) * 16 + l16) * 8];
        acc[0][0] = __builtin_amdgcn_mfma_f32_16x16x32_bf16(a0, b0, acc[0][0], 0, 0, 0);
        acc[0][1] = __builtin_amdgcn_mfma_f32_16x16x32_bf16(a0, b1, acc[0][1], 0, 0, 0);
        acc[1][0] = __builtin_amdgcn_mfma_f32_16x16x32_bf16(a1, b0, acc[1][0], 0, 0, 0);
        acc[1][1] = __builtin_amdgcn_mfma_f32_16x16x32_bf16(a1, b1, acc[1][1], 0, 0, 0);
    }
    #pragma unroll
    for (int rt = 0; rt < 2; ++rt) {
        #pragma unroll
        for (int ci = 0; ci < 2; ++ci) {
            int colg = (c0 + ci) * 16 + l16;
            float w0 = W1r[0][colg], w1 = W1r[1][colg];
            #pragma unroll
            for (int reg = 0; reg < 4; ++reg) {
                int row = rt * 16 + quad * 4 + reg;
                int g = nb + row;
                if (g < N_NODESC) {
                    float v = acc[rt][ci][reg] + xsp[row][0] * w0 + xsp[row][1] * w1;
                    xp1[(long)g * 128 + colg] = v;
                    xp1b[(long)g * 128 + colg] = f2s(v);
                }
            }
        }
    }
}

// ---------------- Layer 1 attention logits ----------------

__global__ __launch_bounds__(256) void logits1_k(
        const float* __restrict__ xp1, const void* __restrict__ as1,
        const void* __restrict__ ad1, const int* __restrict__ flags,
        float* __restrict__ alsrc, float* __restrict__ aldst) {
    const int fp32 = flags[0];
    const int wid = threadIdx.x >> 6, lane = threadIdx.x & 63;
    const int n = blockIdx.x * 4 + wid;
    if (n >= N_NODESC) return;
    float v0 = xp1[(long)n * 128 + lane];
    float v1 = xp1[(long)n * 128 + 64 + lane];
    float s0 = v0 * ldf(as1, lane, fp32), d0 = v0 * ldf(ad1, lane, fp32);
    float s1 = v1 * ldf(as1, 64 + lane, fp32), d1 = v1 * ldf(ad1, 64 + lane, fp32);
    #pragma unroll
    for (int off = 32; off; off >>= 1) {
        s0 += __shfl_xor(s0, off, 64);
        d0 += __shfl_xor(d0, off, 64);
        s1 += __shfl_xor(s1, off, 64);
        d1 += __shfl_xor(d1, off, 64);
    }
    if (lane == 0) {
        alsrc[n * 2] = s0;  aldst[n * 2] = d0;
        alsrc[n * 2 + 1] = s1;  aldst[n * 2 + 1] = d1;
    }
}

// ---------------- Layer 1 aggregation (bf16 gather) ----------------

__global__ __launch_bounds__(256) void agg1_k(
        const int* __restrict__ row_start, const int* __restrict__ col,
        const short* __restrict__ xp1b, const float* __restrict__ alsrc,
        const float* __restrict__ aldst, const void* __restrict__ b1,
        const int* __restrict__ flags, short* __restrict__ h1b) {
    const int fp32 = flags[0];
    const int wid = threadIdx.x >> 6;
    const int lane = threadIdx.x & 63;
    const int gw = blockIdx.x * 4 + wid;
    const int n = gw >> 1, h = gw & 1;
    __shared__ float2 pbuf[4][64];
    if (n >= N_NODESC) return;
    float2* mybuf = pbuf[wid];
    const float ad = aldst[n * 2 + h];
    float e0 = alsrc[n * 2 + h] + ad;
    e0 = e0 > 0.f ? e0 : 0.2f * e0;
    float m = e0, l = 1.f;
    float acc = s2f(xp1b[(long)n * 128 + h * 64 + lane]);
    const int beg = row_start[n], end = row_start[n + 1];
    for (int base = beg; base < end; base += 64) {
        const int idx = base + lane;
        const int valid = idx < end;
        int s = valid ? col[idx] : 0;
        float e = -3.0e38f;
        if (valid) {
            float t = alsrc[s * 2 + h] + ad;
            e = t > 0.f ? t : 0.2f * t;
        }
        float M = e;
        #pragma unroll
        for (int off = 32; off; off >>= 1) M = fmaxf(M, __shfl_xor(M, off, 64));
        if (M > m) { float sc = __expf(m - M); l *= sc; acc *= sc; m = M; }
        float p = valid ? __expf(e - m) : 0.f;
        float ps = p;
        #pragma unroll
        for (int off = 32; off; off >>= 1) ps += __shfl_xor(ps, off, 64);
        l += ps;
        mybuf[lane] = make_float2(p, __int_as_float(s));
        int cnt = end - base; if (cnt > 64) cnt = 64;
        int j = 0;
        for (; j + 4 <= cnt; j += 4) {
            float2 a0 = mybuf[j], a1 = mybuf[j + 1], a2 = mybuf[j + 2], a3 = mybuf[j + 3];
            float x0 = s2f(xp1b[(long)__float_as_int(a0.y) * 128 + h * 64 + lane]);
            float x1 = s2f(xp1b[(long)__float_as_int(a1.y) * 128 + h * 64 + lane]);
            float x2 = s2f(xp1b[(long)__float_as_int(a2.y) * 128 + h * 64 + lane]);
            float x3 = s2f(xp1b[(long)__float_as_int(a3.y) * 128 + h * 64 + lane]);
            acc = fmaf(a0.x, x0, acc);
            acc = fmaf(a1.x, x1, acc);
            acc = fmaf(a2.x, x2, acc);
            acc = fmaf(a3.x, x3, acc);
        }
        for (; j < cnt; ++j) {
            float2 a = mybuf[j];
            acc = fmaf(a.x, s2f(xp1b[(long)__float_as_int(a.y) * 128 + h * 64 + lane]), acc);
        }
    }
    h1b[(long)n * 128 + h * 64 + lane] = f2s(acc / l + ldf(b1, h * 64 + lane, fp32));
}

// ---------------- Layer 2 GEMM via MFMA: h1[50000,128] @ W2[128,64] ----------------

__global__ __launch_bounds__(256) void gemm2_k(
        const short* __restrict__ h1b, const void* __restrict__ W2,
        const int* __restrict__ flags, float* __restrict__ xp2,
        short* __restrict__ xp2b) {
    const int fp32 = flags[0];
    const int tid = threadIdx.x;
    const int nb = blockIdx.x * 32;
    __shared__ __align__(16) short W2s[8192];
    __shared__ __align__(16) short xs[32][136];

    #pragma unroll
    for (int i = 0; i < 32; ++i) {
        int idx = i * 256 + tid;
        int k = idx >> 6, n = idx & 63;
        float v = ldf(W2, (long)k * 64 + n, fp32);
        int c = n >> 4, nn = n & 15, t = k >> 5, q = (k >> 3) & 3, j = k & 7;
        W2s[(((c * 4 + t) * 4 + q) * 16 + nn) * 8 + j] = f2s(v);
    }
    #pragma unroll
    for (int i = 0; i < 8; ++i) {
        int idx = i * 256 + tid;
        int r = idx >> 6, ii = idx & 63;
        int g = nb + r;
        int val = (g < N_NODESC) ? ((const int*)h1b)[(long)g * 64 + ii] : 0;
        ((int*)&xs[r][0])[ii] = val;
    }
    __syncthreads();

    const int wid = tid >> 6, lane = tid & 63;
    const int quad = lane >> 4, l16 = lane & 15;
    floatx4 acc0 = (floatx4){0.f, 0.f, 0.f, 0.f};
    floatx4 acc1 = (floatx4){0.f, 0.f, 0.f, 0.f};
    #pragma unroll
    for (int t = 0; t < 4; ++t) {
        short8 a0 = *(const short8*)&xs[l16][t * 32 + quad * 8];
        short8 a1 = *(const short8*)&xs[16 + l16][t * 32 + quad * 8];
        short8 b = *(const short8*)&W2s[(((wid * 4 + t) * 4 + quad) * 16 + l16) * 8];
        acc0 = __builtin_amdgcn_mfma_f32_16x16x32_bf16(a0, b, acc0, 0, 0, 0);
        acc1 = __builtin_amdgcn_mfma_f32_16x16x32_bf16(a1, b, acc1, 0, 0, 0);
    }
    const int colg = wid * 16 + l16;
    #pragma unroll
    for (int reg = 0; reg < 4; ++reg) {
        int g0 = nb + quad * 4 + reg;
        int g1 = g0 + 16;
        if (g0 < N_NODESC) {
            xp2[(long)g0 * 64 + colg] = acc0[reg];
            xp2b[(long)g0 * 64 + colg] = f2s(acc0[reg]);
        }
        if (g1 < N_NODESC) {
            xp2[(long)g1 * 64 + colg] = acc1[reg];
            xp2b[(long)g1 * 64 + colg] = f2s(acc1[reg]);
        }
    }
}

// ---------------- Layer 2 attention logits ----------------

__global__ __launch_bounds__(256) void logits2_k(
        const float* __restrict__ xp2, const void* __restrict__ as2,
        const void* __restrict__ ad2, const int* __restrict__ flags,
        float* __restrict__ alsrc, float* __restrict__ aldst) {
    const int fp32 = flags[0];
    const int wid = threadIdx.x >> 6, lane = threadIdx.x & 63;
    const int n = blockIdx.x * 4 + wid;
    if (n >= N_NODESC) return;
    float v = xp2[(long)n * 64 + lane];
    float s = v * ldf(as2, lane, fp32), d = v * ldf(ad2, lane, fp32);
    #pragma unroll
    for (int off = 32; off; off >>= 1) {
        s += __shfl_xor(s, off, 64);
        d += __shfl_xor(d, off, 64);
    }
    if (lane == 0) { alsrc[n] = s; aldst[n] = d; }
}

// ---------------- Layer 2 aggregation (bf16 gather) ----------------

__global__ __launch_bounds__(256) void agg2_k(
        const int* __restrict__ row_start, const int* __restrict__ col,
        const short* __restrict__ xp2b, const float* __restrict__ alsrc,
        const float* __restrict__ aldst, const void* __restrict__ b2v,
        const int* __restrict__ flags, float* __restrict__ h2) {
    const int fp32 = flags[0];
    const int wid = threadIdx.x >> 6;
    const int lane = threadIdx.x & 63;
    const int n = blockIdx.x * 4 + wid;
    __shared__ float2 pbuf[4][64];
    if (n >= N_NODESC) return;
    float2* mybuf = pbuf[wid];
    const float ad = aldst[n];
    float e0 = alsrc[n] + ad;
    e0 = e0 > 0.f ? e0 : 0.2f * e0;
    float m = e0, l = 1.f;
    float acc = s2f(xp2b[(long)n * 64 + lane]);
    const int beg = row_start[n], end = row_start[n + 1];
    for (int base = beg; base < end; base += 64) {
        const int idx = base + lane;
        const int valid = idx < end;
        int s = valid ? col[idx] : 0;
        float e = -3.0e38f;
        if (valid) {
            float t = alsrc[s] + ad;
            e = t > 0.f ? t : 0.2f * t;
        }
        float M = e;
        #pragma unroll
        for (int off = 32; off; off >>= 1) M = fmaxf(M, __shfl_xor(M, off, 64));
        if (M > m) { float sc = __expf(m - M); l *= sc; acc *= sc; m = M; }
        float p = valid ? __expf(e - m) : 0.f;
        float ps = p;
        #pragma unroll
        for (int off = 32; off; off >>= 1) ps += __shfl_xor(ps, off, 64);
        l += ps;
        mybuf[lane] = make_float2(p, __int_as_float(s));
        int cnt = end - base; if (cnt > 64) cnt = 64;
        int j = 0;
        for (; j + 4 <= cnt; j += 4) {
            float2 a0 = mybuf[j], a1 = mybuf[j + 1], a2 = mybuf[j + 2], a3 = mybuf[j + 3];
            float x0 = s2f(xp2b[(long)__float_as_int(a0.y) * 64 + lane]);
            float x1 = s2f(xp2b[(long)__float_as_int(a1.y) * 64 + lane]);
            float x2 = s2f(xp2b[(long)__float_as_int(a2.y) * 64 + lane]);
            float x3 = s2f(xp2b[(long)__float_as_int(a3.y) * 64 + lane]);
            acc = fmaf(a0.x, x0, acc);
            acc = fmaf(a1.x, x1, acc);
            acc = fmaf(a2.x, x2, acc);
            acc = fmaf(a3.x, x3, acc);
        }
        for (; j < cnt; ++j) {
            float2 a = mybuf[j];
            acc = fmaf(a.x, s2f(xp2b[(long)__float_as_int(a.y) * 64 + lane]), acc);
        }
    }
    h2[(long)n * 64 + lane] = acc / l + ldf(b2v, lane, fp32);
}

// ---------------- mean pool ----------------

__global__ __launch_bounds__(64) void pool_k(const float* __restrict__ h2,
                                             const int* __restrict__ batch,
                                             float* __restrict__ pooled,
                                             float* __restrict__ counts) {
    const int c = threadIdx.x;
    int lo = blockIdx.x * POOL_CHUNK;
    int hi = lo + POOL_CHUNK;
    if (hi > N_NODESC) hi = N_NODESC;
    if (lo >= N_NODESC) return;
    int cur = batch[lo];
    float acc = 0.f;
    int cnt = 0;
    for (int i = lo; i < hi; ++i) {
        int g = batch[i];
        if (g != cur) {
            atomicAdd(&pooled[cur * 64 + c], acc);
            if (c == 0) atomicAdd(&counts[cur], (float)cnt);
            acc = 0.f; cnt = 0; cur = g;
        }
        acc += h2[(long)i * 64 + c];
        cnt++;
    }
    atomicAdd(&pooled[cur * 64 + c], acc);
    if (c == 0) atomicAdd(&counts[cur], (float)cnt);
}

// ---------------- decoder MLP ----------------

__global__ __launch_bounds__(64) void dec_k(const float* __restrict__ pooled,
                                            const float* __restrict__ counts,
                                            const void* __restrict__ Wd1, const void* __restrict__ bd1,
                                            const void* __restrict__ Wd2, const void* __restrict__ bd2,
                                            const int* __restrict__ flags,
                                            void* __restrict__ out) {
    const int fp32 = flags[0];
    const int g = blockIdx.x, j = threadIdx.x;
    __shared__ float p[64], dh[64];
    float cnt = counts[g];
    cnt = cnt < 1.f ? 1.f : cnt;
    p[j] = pooled[g * 64 + j] / cnt;
    __syncthreads();
    float acc = ldf(bd1, j, fp32);
    for (int k = 0; k < 64; ++k) acc += p[k] * ldf(Wd1, k * 64 + j, fp32);
    dh[j] = acc > 0.f ? acc : 0.f;
    __syncthreads();
    if (j < 32) {
        float o = ldf(bd2, j, fp32);
        for (int k = 0; k < 64; ++k) o += dh[k] * ldf(Wd2, k * 32 + j, fp32);
        if (fp32) ((float*)out)[g * 32 + j] = o;
        else      ((bf16*)out)[g * 32 + j] = __float2bfloat16(o);
    }
}

extern "C" void kernel_launch(void* const* d_in, const int* in_sizes, int n_in,
                              void* d_out, int out_size, void* d_ws, size_t ws_size,
                              hipStream_t stream) {
    (void)in_sizes; (void)n_in; (void)out_size; (void)ws_size;
    const void* prot = d_in[0];
    const void* sp   = d_in[1];
    const void* lri  = d_in[2];
    const void* eidx = d_in[3];
    const void* batch= d_in[4];
    const void* W1   = d_in[5];
    const void* as1  = d_in[6];
    const void* ad1  = d_in[7];
    const void* b1   = d_in[8];
    const void* W2   = d_in[9];
    const void* as2  = d_in[10];
    const void* ad2  = d_in[11];
    const void* b2v  = d_in[12];
    const void* Wd1  = d_in[13];
    const void* bd1  = d_in[14];
    const void* Wd2  = d_in[15];
    const void* bd2  = d_in[16];

    char* w = (char*)d_ws;
    auto alloc = [&](size_t bytes) -> void* {
        char* p = w;
        w += (bytes + 255) & ~(size_t)255;
        return (void*)p;
    };
    int*   flags     = (int*)alloc(2 * 4);
    int*   edges32   = (int*)alloc((size_t)2 * N_EDGESC * 4);
    int*   batch32   = (int*)alloc((size_t)N_NODESC * 4);
    int*   deg       = (int*)alloc((size_t)N_NODESC * 4);
    int*   row_start = (int*)alloc((size_t)(N_NODESC + 1) * 4);
    int*   cursor    = (int*)alloc((size_t)N_NODESC * 4);
    int*   blocksum  = (int*)alloc((size_t)SCAN_NB * 4);
    int*   blockoff  = (int*)alloc((size_t)SCAN_NB * 4);
    int*   col       = (int*)alloc((size_t)N_EDGESC * 4);
    float* xp1       = (float*)alloc((size_t)N_NODESC * 128 * 4);
    short* xp1b      = (short*)alloc((size_t)N_NODESC * 128 * 2);
    float* alsrc1    = (float*)alloc((size_t)N_NODESC * 2 * 4);
    float* aldst1    = (float*)alloc((size_t)N_NODESC * 2 * 4);
    short* h1b       = (short*)alloc((size_t)N_NODESC * 128 * 2);
    float* xp2       = (float*)alloc((size_t)N_NODESC * 64 * 4);
    short* xp2b      = (short*)alloc((size_t)N_NODESC * 64 * 2);
    float* alsrc2    = (float*)alloc((size_t)N_NODESC * 4);
    float* aldst2    = (float*)alloc((size_t)N_NODESC * 4);
    float* h2        = (float*)alloc((size_t)N_NODESC * 64 * 4);
    float* pooled    = (float*)alloc((size_t)NUM_GRAPHSC * 64 * 4);
    float* counts    = (float*)alloc((size_t)NUM_GRAPHSC * 4);

    detect_k<<<1, 64, 0, stream>>>(prot, eidx, flags);
    zero_k<<<(N_NODESC + 255) / 256, 256, 0, stream>>>(deg, N_NODESC);
    zero_k<<<(NUM_GRAPHSC * 64 + 255) / 256, 256, 0, stream>>>((int*)pooled, NUM_GRAPHSC * 64);
    zero_k<<<1, 256, 0, stream>>>((int*)counts, NUM_GRAPHSC);
    cvt_hist_k<<<(N_EDGESC + 255) / 256, 256, 0, stream>>>(eidx, edges32, deg, flags);
    cvt_batch_k<<<(N_NODESC + 255) / 256, 256, 0, stream>>>(batch, batch32, flags);

    const int* srcv = edges32;
    const int* dstv = edges32 + N_EDGESC;

    partial_k<<<SCAN_NB, SCAN_B, 0, stream>>>(deg, blocksum);
    scanpart_k<<<1, SCAN_B, 0, stream>>>(blocksum, blockoff);
    scanwrite_k<<<SCAN_NB, SCAN_B, 0, stream>>>(deg, blockoff, row_start, cursor);
    {
        const int nchunk = (N_EDGESC + EPB - 1) / EPB;
        scatter_k<<<nchunk * 8, 256, 0, stream>>>(srcv, dstv, cursor, col);
    }

    const int nblk = (N_NODESC + 31) / 32;
    gemm1_k<<<nblk, 256, 0, stream>>>(prot, sp, lri, W1, flags, xp1, xp1b);
    logits1_k<<<(N_NODESC + 3) / 4, 256, 0, stream>>>(xp1, as1, ad1, flags, alsrc1, aldst1);
    agg1_k<<<(2 * N_NODESC + 3) / 4, 256, 0, stream>>>(row_start, col, xp1b, alsrc1, aldst1, b1, flags, h1b);
    gemm2_k<<<nblk, 256, 0, stream>>>(h1b, W2, flags, xp2, xp2b);
    logits2_k<<<(N_NODESC + 3) / 4, 256, 0, stream>>>(xp2, as2, ad2, flags, alsrc2, aldst2);
    agg2_k<<<(N_NODESC + 3) / 4, 256, 0, stream>>>(row_start, col, xp2b, alsrc2, aldst2, b2v, flags, h2);
    pool_k<<<(N_NODESC + POOL_CHUNK - 1) / POOL_CHUNK, 64, 0, stream>>>(h2, batch32, pooled, counts);
    dec_k<<<NUM_GRAPHSC, 64, 0, stream>>>(pooled, counts, Wd1, bd1, Wd2, bd2, flags, d_out);
}

// Round 7
// 468.383 us; speedup vs baseline: 2.6615x; 1.2214x over previous
//
#include <hip/hip_runtime.h>
#include <hip/hip_bf16.h>

#define N_NODESC 50000
#define N_EDGESC 1600000
#define IN_DIMC 130
#define NUM_GRAPHSC 64
#define POOL_CHUNK 128
#define SLICE_W 6250          // 50000 / 8
#define EPB 8192              // edges per chunk in sliced scatter
#define SCAN_B 256
#define SCAN_NB ((N_NODESC + SCAN_B - 1) / SCAN_B)   // 196

typedef __hip_bfloat16 bf16;
typedef short short8 __attribute__((ext_vector_type(8)));
typedef float floatx4 __attribute__((ext_vector_type(4)));

__device__ __forceinline__ float b2f(bf16 v) { return __bfloat162float(v); }
__device__ __forceinline__ float ldf(const void* p, long i, int fp32) {
    return fp32 ? ((const float*)p)[i] : __bfloat162float(((const bf16*)p)[i]);
}
__device__ __forceinline__ short f2s(float v) {
    bf16 h = __float2bfloat16(v);
    return *(short*)&h;
}
__device__ __forceinline__ unsigned pack2(float lo, float hi) {
    bf16 a = __float2bfloat16(lo), b = __float2bfloat16(hi);
    unsigned ua = *(unsigned short*)&a, ub = *(unsigned short*)&b;
    return (ub << 16) | ua;
}

// ---------------- dtype detection ----------------
__global__ void detect_k(const void* __restrict__ prot,
                         const void* __restrict__ eidx,
                         int* __restrict__ flags) {
    if (blockIdx.x == 0 && threadIdx.x == 0) {
        const bf16* pb = (const bf16*)prot;
        int sane = 0;
        for (int i = 0; i < 64; ++i) {
            float a = fabsf(__bfloat162float(pb[2 * i]));
            if (a > 1e-8f && a < 1e4f) sane++;
        }
        flags[0] = (sane >= 48) ? 0 : 1;
        const unsigned* u = (const unsigned*)eidx;
        int zhi = 0;
        for (int i = 0; i < 32; ++i)
            if (u[2 * i + 1] == 0u) zhi++;
        flags[1] = (zhi >= 30) ? 1 : 0;
    }
}

// ---------------- weight prep: frag-major bf16 tables in global ----------------
// K-order for layer 1: [prot 0..63, lri 0..63, (sp0, sp1 as rank-2 remainder)]
__global__ __launch_bounds__(256) void prep_k(const void* __restrict__ W1,
                                              const void* __restrict__ W2,
                                              const int* __restrict__ flags,
                                              short* __restrict__ w1f,
                                              float* __restrict__ w1r,
                                              short* __restrict__ w2f) {
    const int fp32 = flags[0];
    const int b = blockIdx.x, tid = threadIdx.x;
    if (b < 64) {
        int idx = b * 256 + tid;                    // 16384
        int kp = idx >> 7, n = idx & 127;
        int krow = kp < 64 ? kp : 66 + (kp - 64);
        float v = ldf(W1, (long)krow * 128 + n, fp32);
        int c = n >> 4, nn = n & 15, t = kp >> 5, q = (kp >> 3) & 3, j = kp & 7;
        w1f[(((c * 4 + t) * 4 + q) * 16 + nn) * 8 + j] = f2s(v);
    } else if (b == 64) {
        int which = tid >> 7, n = tid & 127;        // W1 rows 64,65 (spatial)
        w1r[which * 128 + n] = ldf(W1, (long)(64 + which) * 128 + n, fp32);
    } else {
        int idx = (b - 65) * 256 + tid;             // 8192
        int k = idx >> 6, n = idx & 63;
        float v = ldf(W2, (long)k * 64 + n, fp32);
        int c = n >> 4, nn = n & 15, t = k >> 5, q = (k >> 3) & 3, j = k & 7;
        w2f[(((c * 4 + t) * 4 + q) * 16 + nn) * 8 + j] = f2s(v);
    }
}

// fused: int64->int32 edge convert + dst histogram
__global__ __launch_bounds__(256) void cvt_hist_k(const void* __restrict__ eidx,
                                                  int* __restrict__ edges32,
                                                  int* __restrict__ deg,
                                                  const int* __restrict__ flags) {
    const int i64f = flags[1];
    int e = blockIdx.x * 256 + threadIdx.x;
    if (e < N_EDGESC) {
        int s, d;
        if (i64f) {
            s = (int)((const long long*)eidx)[e];
            d = (int)((const long long*)eidx)[N_EDGESC + e];
        } else {
            s = ((const int*)eidx)[e];
            d = ((const int*)eidx)[N_EDGESC + e];
        }
        edges32[e] = s;
        edges32[N_EDGESC + e] = d;
        atomicAdd(&deg[d], 1);
    }
}

__global__ __launch_bounds__(256) void cvt_batch_k(const void* __restrict__ b,
                                                   int* __restrict__ b32,
                                                   const int* __restrict__ flags) {
    const int i64f = flags[1];
    int i = blockIdx.x * 256 + threadIdx.x;
    if (i < N_NODESC)
        b32[i] = i64f ? (int)((const long long*)b)[i] : ((const int*)b)[i];
}

__global__ __launch_bounds__(256) void zero_k(int* __restrict__ p, int n) {
    int i = blockIdx.x * 256 + threadIdx.x;
    if (i < n) p[i] = 0;
}

// ---------------- multi-block exclusive scan of deg ----------------

__global__ __launch_bounds__(SCAN_B) void partial_k(const int* __restrict__ deg,
                                                    int* __restrict__ blocksum) {
    const int tid = threadIdx.x;
    const int i = blockIdx.x * SCAN_B + tid;
    int v = (i < N_NODESC) ? deg[i] : 0;
    #pragma unroll
    for (int off = 32; off; off >>= 1) v += __shfl_xor(v, off, 64);
    __shared__ int ws[4];
    if ((tid & 63) == 0) ws[tid >> 6] = v;
    __syncthreads();
    if (tid == 0) blocksum[blockIdx.x] = ws[0] + ws[1] + ws[2] + ws[3];
}

__global__ __launch_bounds__(SCAN_B) void scanpart_k(int* __restrict__ blocksum,
                                                     int* __restrict__ blockoff) {
    __shared__ int s[SCAN_B];
    const int tid = threadIdx.x;
    int v = (tid < SCAN_NB) ? blocksum[tid] : 0;
    s[tid] = v;
    __syncthreads();
    for (int off = 1; off < SCAN_B; off <<= 1) {
        int t = (tid >= off) ? s[tid - off] : 0;
        __syncthreads();
        s[tid] += t;
        __syncthreads();
    }
    if (tid < SCAN_NB) blockoff[tid] = s[tid] - v;   // exclusive
}

__global__ __launch_bounds__(SCAN_B) void scanwrite_k(const int* __restrict__ deg,
                                                      const int* __restrict__ blockoff,
                                                      int* __restrict__ row_start,
                                                      int* __restrict__ cursor) {
    __shared__ int s[SCAN_B];
    const int tid = threadIdx.x;
    const int i = blockIdx.x * SCAN_B + tid;
    int d = (i < N_NODESC) ? deg[i] : 0;
    s[tid] = d;
    __syncthreads();
    for (int off = 1; off < SCAN_B; off <<= 1) {
        int t = (tid >= off) ? s[tid - off] : 0;
        __syncthreads();
        s[tid] += t;
        __syncthreads();
    }
    int excl = s[tid] - d + blockoff[blockIdx.x];
    if (i < N_NODESC) {
        row_start[i] = excl;
        cursor[i] = excl;
        if (i == N_NODESC - 1) row_start[N_NODESC] = excl + d;
    }
}

// XCD-sliced scatter
__global__ __launch_bounds__(256) void scatter_k(const int* __restrict__ srcv,
                                                 const int* __restrict__ dstv,
                                                 int* __restrict__ cursor,
                                                 int* __restrict__ col) {
    const int slice = blockIdx.x & 7;
    const int chunk = blockIdx.x >> 3;
    const int lo = slice * SLICE_W, hi = lo + SLICE_W;
    int e = chunk * EPB + threadIdx.x;
    int eend = (chunk + 1) * EPB;
    if (eend > N_EDGESC) eend = N_EDGESC;
    for (; e < eend; e += 256) {
        int d = dstv[e];
        if (d >= lo && d < hi) {
            int pos = atomicAdd(&cursor[d], 1);
            col[pos] = srcv[e];
        }
    }
}

// ---------------- Layer 1 GEMM via MFMA (B-frags from global prep table) ----------------

__global__ __launch_bounds__(256) void gemm1_k(
        const void* __restrict__ prot, const void* __restrict__ sp,
        const void* __restrict__ lri,
        const short* __restrict__ w1f, const float* __restrict__ w1r,
        const int* __restrict__ flags, float* __restrict__ xp1,
        short* __restrict__ xp1b) {
    const int fp32 = flags[0];
    const int tid = threadIdx.x;
    const int nb = blockIdx.x * 32;
    __shared__ __align__(16) short xs[32][136];   // K order: prot 0..63, lri 0..63
    __shared__ float xsp[32][2];                  // spatial remainder

    if (!fp32) {
        #pragma unroll
        for (int i = 0; i < 2; ++i) {
            int cidx = i * 256 + tid;             // 512 chunks of 8 shorts
            int r = cidx >> 4, cc = cidx & 15;
            int g = nb + r;
            short8 v = (short8){0, 0, 0, 0, 0, 0, 0, 0};
            if (g < N_NODESC) {
                const short* srcp = (cc < 8)
                    ? (const short*)prot + (long)g * 64 + cc * 8
                    : (const short*)lri + (long)g * 64 + (cc - 8) * 8;
                v = *(const short8*)srcp;
            }
            *(short8*)&xs[r][cc * 8] = v;
        }
    } else {
        #pragma unroll
        for (int i = 0; i < 16; ++i) {
            int idx = i * 256 + tid;
            int r = idx >> 7, k = idx & 127;
            int g = nb + r;
            float v = 0.f;
            if (g < N_NODESC)
                v = (k < 64) ? ((const float*)prot)[(long)g * 64 + k]
                             : ((const float*)lri)[(long)g * 64 + (k - 64)];
            xs[r][k] = f2s(v);
        }
    }
    if (tid < 64) {
        int r = tid >> 1, which = tid & 1;
        int g = nb + r;
        xsp[r][which] = (g < N_NODESC) ? ldf(sp, (long)g * 2 + which, fp32) : 0.f;
    }
    __syncthreads();

    const int wid = tid >> 6, lane = tid & 63;
    const int quad = lane >> 4, l16 = lane & 15;
    floatx4 acc[2][2];
    #pragma unroll
    for (int a = 0; a < 2; ++a)
        #pragma unroll
        for (int b = 0; b < 2; ++b) acc[a][b] = (floatx4){0.f, 0.f, 0.f, 0.f};

    const int c0 = 2 * wid;
    #pragma unroll
    for (int t = 0; t < 4; ++t) {
        short8 a0 = *(const short8*)&xs[l16][t * 32 + quad * 8];
        short8 a1 = *(const short8*)&xs[16 + l16][t * 32 + quad * 8];
        short8 b0 = *(const short8*)&w1f[(((c0 * 4 + t) * 4 + quad) * 16 + l16) * 8];
        short8 b1 = *(const short8*)&w1f[((((c0 + 1) * 4 + t) * 4 + quad) * 16 + l16) * 8];
        acc[0][0] = __builtin_amdgcn_mfma_f32_16x16x32_bf16(a0, b0, acc[0][0], 0, 0, 0);
        acc[0][1] = __builtin_amdgcn_mfma_f32_16x16x32_bf16(a0, b1, acc[0][1], 0, 0, 0);
        acc[1][0] = __builtin_amdgcn_mfma_f32_16x16x32_bf16(a1, b0, acc[1][0], 0, 0, 0);
        acc[1][1] = __builtin_amdgcn_mfma_f32_16x16x32_bf16(a1, b1, acc[1][1], 0, 0, 0);
    }
    #pragma unroll
    for (int rt = 0; rt < 2; ++rt) {
        #pragma unroll
        for (int ci = 0; ci < 2; ++ci) {
            int colg = (c0 + ci) * 16 + l16;
            float w0 = w1r[colg], w1v = w1r[128 + colg];
            #pragma unroll
            for (int reg = 0; reg < 4; ++reg) {
                int row = rt * 16 + quad * 4 + reg;
                int g = nb + row;
                if (g < N_NODESC) {
                    float v = acc[rt][ci][reg] + xsp[row][0] * w0 + xsp[row][1] * w1v;
                    xp1[(long)g * 128 + colg] = v;
                    xp1b[(long)g * 128 + colg] = f2s(v);
                }
            }
        }
    }
}

// ---------------- Layer 1 attention logits ----------------

__global__ __launch_bounds__(256) void logits1_k(
        const float* __restrict__ xp1, const void* __restrict__ as1,
        const void* __restrict__ ad1, const int* __restrict__ flags,
        float* __restrict__ alsrc, float* __restrict__ aldst) {
    const int fp32 = flags[0];
    const int wid = threadIdx.x >> 6, lane = threadIdx.x & 63;
    const int n = blockIdx.x * 4 + wid;
    if (n >= N_NODESC) return;
    float v0 = xp1[(long)n * 128 + lane];
    float v1 = xp1[(long)n * 128 + 64 + lane];
    float s0 = v0 * ldf(as1, lane, fp32), d0 = v0 * ldf(ad1, lane, fp32);
    float s1 = v1 * ldf(as1, 64 + lane, fp32), d1 = v1 * ldf(ad1, 64 + lane, fp32);
    #pragma unroll
    for (int off = 32; off; off >>= 1) {
        s0 += __shfl_xor(s0, off, 64);
        d0 += __shfl_xor(d0, off, 64);
        s1 += __shfl_xor(s1, off, 64);
        d1 += __shfl_xor(d1, off, 64);
    }
    if (lane == 0) {
        alsrc[n * 2] = s0;  aldst[n * 2] = d0;
        alsrc[n * 2 + 1] = s1;  aldst[n * 2 + 1] = d1;
    }
}

// ---------------- Layer 1 aggregation: one wave per node, BOTH heads ----------------
// Lane owns channels {2*lane, 2*lane+1} (one uint of the bf16 row).

__global__ __launch_bounds__(256) void agg1_k(
        const int* __restrict__ row_start, const int* __restrict__ col,
        const unsigned* __restrict__ xp1b32, const float2* __restrict__ als2,
        const float* __restrict__ aldst, const void* __restrict__ b1,
        const int* __restrict__ flags, unsigned* __restrict__ h1b32) {
    const int fp32 = flags[0];
    const int wid = threadIdx.x >> 6;
    const int lane = threadIdx.x & 63;
    const int n = blockIdx.x * 4 + wid;
    __shared__ float4 pbuf[4][64];
    if (n >= N_NODESC) return;
    float4* mybuf = pbuf[wid];
    const float ad0 = aldst[2 * n], ad1 = aldst[2 * n + 1];
    float2 a0 = als2[n];
    float e00 = a0.x + ad0; e00 = e00 > 0.f ? e00 : 0.2f * e00;
    float e01 = a0.y + ad1; e01 = e01 > 0.f ? e01 : 0.2f * e01;
    float m0 = e00, l0 = 1.f, m1 = e01, l1 = 1.f;
    unsigned u = xp1b32[(long)n * 64 + lane];
    float accL = __uint_as_float(u << 16);
    float accH = __uint_as_float(u & 0xffff0000u);
    const int beg = row_start[n], end = row_start[n + 1];
    for (int base = beg; base < end; base += 64) {
        const int idx = base + lane;
        const int valid = idx < end;
        int s = valid ? col[idx] : 0;
        float e0 = -3.0e38f, e1 = -3.0e38f;
        if (valid) {
            float2 av = als2[s];
            float t0 = av.x + ad0; e0 = t0 > 0.f ? t0 : 0.2f * t0;
            float t1 = av.y + ad1; e1 = t1 > 0.f ? t1 : 0.2f * t1;
        }
        float M0 = e0, M1 = e1;
        #pragma unroll
        for (int off = 32; off; off >>= 1) {
            M0 = fmaxf(M0, __shfl_xor(M0, off, 64));
            M1 = fmaxf(M1, __shfl_xor(M1, off, 64));
        }
        float nm0 = fmaxf(m0, M0), nm1 = fmaxf(m1, M1);
        float sc0 = __expf(m0 - nm0), sc1 = __expf(m1 - nm1);
        l0 *= sc0; l1 *= sc1; m0 = nm0; m1 = nm1;
        float sc = lane < 32 ? sc0 : sc1;
        accL *= sc; accH *= sc;
        float p0 = valid ? __expf(e0 - m0) : 0.f;
        float p1 = valid ? __expf(e1 - m1) : 0.f;
        float ps0 = p0, ps1 = p1;
        #pragma unroll
        for (int off = 32; off; off >>= 1) {
            ps0 += __shfl_xor(ps0, off, 64);
            ps1 += __shfl_xor(ps1, off, 64);
        }
        l0 += ps0; l1 += ps1;
        mybuf[lane] = make_float4(p0, p1, __int_as_float(s), 0.f);
        int cnt = end - base; if (cnt > 64) cnt = 64;
        int j = 0;
        for (; j + 4 <= cnt; j += 4) {
            float4 b0 = mybuf[j], b1v = mybuf[j + 1], b2 = mybuf[j + 2], b3 = mybuf[j + 3];
            unsigned x0 = xp1b32[(long)__float_as_int(b0.z) * 64 + lane];
            unsigned x1 = xp1b32[(long)__float_as_int(b1v.z) * 64 + lane];
            unsigned x2 = xp1b32[(long)__float_as_int(b2.z) * 64 + lane];
            unsigned x3 = xp1b32[(long)__float_as_int(b3.z) * 64 + lane];
            float p0v = lane < 32 ? b0.x : b0.y;
            float p1v = lane < 32 ? b1v.x : b1v.y;
            float p2v = lane < 32 ? b2.x : b2.y;
            float p3v = lane < 32 ? b3.x : b3.y;
            accL = fmaf(p0v, __uint_as_float(x0 << 16), accL);
            accH = fmaf(p0v, __uint_as_float(x0 & 0xffff0000u), accH);
            accL = fmaf(p1v, __uint_as_float(x1 << 16), accL);
            accH = fmaf(p1v, __uint_as_float(x1 & 0xffff0000u), accH);
            accL = fmaf(p2v, __uint_as_float(x2 << 16), accL);
            accH = fmaf(p2v, __uint_as_float(x2 & 0xffff0000u), accH);
            accL = fmaf(p3v, __uint_as_float(x3 << 16), accL);
            accH = fmaf(p3v, __uint_as_float(x3 & 0xffff0000u), accH);
        }
        for (; j < cnt; ++j) {
            float4 bv = mybuf[j];
            unsigned x = xp1b32[(long)__float_as_int(bv.z) * 64 + lane];
            float pv = lane < 32 ? bv.x : bv.y;
            accL = fmaf(pv, __uint_as_float(x << 16), accL);
            accH = fmaf(pv, __uint_as_float(x & 0xffff0000u), accH);
        }
    }
    float lh = lane < 32 ? l0 : l1;
    float outL = accL / lh + ldf(b1, 2 * lane, fp32);
    float outH = accH / lh + ldf(b1, 2 * lane + 1, fp32);
    h1b32[(long)n * 64 + lane] = pack2(outL, outH);
}

// ---------------- Layer 2 GEMM via MFMA (B-frags from global prep table) ----------------

__global__ __launch_bounds__(256) void gemm2_k(
        const unsigned* __restrict__ h1b32, const short* __restrict__ w2f,
        float* __restrict__ xp2, short* __restrict__ xp2b) {
    const int tid = threadIdx.x;
    const int nb = blockIdx.x * 32;
    __shared__ __align__(16) short xs[32][136];

    #pragma unroll
    for (int i = 0; i < 8; ++i) {
        int idx = i * 256 + tid;
        int r = idx >> 6, ii = idx & 63;
        int g = nb + r;
        unsigned val = (g < N_NODESC) ? h1b32[(long)g * 64 + ii] : 0u;
        ((unsigned*)&xs[r][0])[ii] = val;
    }
    __syncthreads();

    const int wid = tid >> 6, lane = tid & 63;
    const int quad = lane >> 4, l16 = lane & 15;
    floatx4 acc0 = (floatx4){0.f, 0.f, 0.f, 0.f};
    floatx4 acc1 = (floatx4){0.f, 0.f, 0.f, 0.f};
    #pragma unroll
    for (int t = 0; t < 4; ++t) {
        short8 a0 = *(const short8*)&xs[l16][t * 32 + quad * 8];
        short8 a1 = *(const short8*)&xs[16 + l16][t * 32 + quad * 8];
        short8 b = *(const short8*)&w2f[(((wid * 4 + t) * 4 + quad) * 16 + l16) * 8];
        acc0 = __builtin_amdgcn_mfma_f32_16x16x32_bf16(a0, b, acc0, 0, 0, 0);
        acc1 = __builtin_amdgcn_mfma_f32_16x16x32_bf16(a1, b, acc1, 0, 0, 0);
    }
    const int colg = wid * 16 + l16;
    #pragma unroll
    for (int reg = 0; reg < 4; ++reg) {
        int g0 = nb + quad * 4 + reg;
        int g1 = g0 + 16;
        if (g0 < N_NODESC) {
            xp2[(long)g0 * 64 + colg] = acc0[reg];
            xp2b[(long)g0 * 64 + colg] = f2s(acc0[reg]);
        }
        if (g1 < N_NODESC) {
            xp2[(long)g1 * 64 + colg] = acc1[reg];
            xp2b[(long)g1 * 64 + colg] = f2s(acc1[reg]);
        }
    }
}

// ---------------- Layer 2 attention logits ----------------

__global__ __launch_bounds__(256) void logits2_k(
        const float* __restrict__ xp2, const void* __restrict__ as2,
        const void* __restrict__ ad2, const int* __restrict__ flags,
        float* __restrict__ alsrc, float* __restrict__ aldst) {
    const int fp32 = flags[0];
    const int wid = threadIdx.x >> 6, lane = threadIdx.x & 63;
    const int n = blockIdx.x * 4 + wid;
    if (n >= N_NODESC) return;
    float v = xp2[(long)n * 64 + lane];
    float s = v * ldf(as2, lane, fp32), d = v * ldf(ad2, lane, fp32);
    #pragma unroll
    for (int off = 32; off; off >>= 1) {
        s += __shfl_xor(s, off, 64);
        d += __shfl_xor(d, off, 64);
    }
    if (lane == 0) { alsrc[n] = s; aldst[n] = d; }
}

// ---------------- Layer 2 aggregation (bf16 gather) ----------------

__global__ __launch_bounds__(256) void agg2_k(
        const int* __restrict__ row_start, const int* __restrict__ col,
        const short* __restrict__ xp2b, const float* __restrict__ alsrc,
        const float* __restrict__ aldst, const void* __restrict__ b2v,
        const int* __restrict__ flags, float* __restrict__ h2) {
    const int fp32 = flags[0];
    const int wid = threadIdx.x >> 6;
    const int lane = threadIdx.x & 63;
    const int n = blockIdx.x * 4 + wid;
    __shared__ float2 pbuf[4][64];
    if (n >= N_NODESC) return;
    float2* mybuf = pbuf[wid];
    const float ad = aldst[n];
    float e0 = alsrc[n] + ad;
    e0 = e0 > 0.f ? e0 : 0.2f * e0;
    float m = e0, l = 1.f;
    float acc = __uint_as_float(((unsigned)(unsigned short)xp2b[(long)n * 64 + lane]) << 16);
    const int beg = row_start[n], end = row_start[n + 1];
    for (int base = beg; base < end; base += 64) {
        const int idx = base + lane;
        const int valid = idx < end;
        int s = valid ? col[idx] : 0;
        float e = -3.0e38f;
        if (valid) {
            float t = alsrc[s] + ad;
            e = t > 0.f ? t : 0.2f * t;
        }
        float M = e;
        #pragma unroll
        for (int off = 32; off; off >>= 1) M = fmaxf(M, __shfl_xor(M, off, 64));
        if (M > m) { float sc = __expf(m - M); l *= sc; acc *= sc; m = M; }
        float p = valid ? __expf(e - m) : 0.f;
        float ps = p;
        #pragma unroll
        for (int off = 32; off; off >>= 1) ps += __shfl_xor(ps, off, 64);
        l += ps;
        mybuf[lane] = make_float2(p, __int_as_float(s));
        int cnt = end - base; if (cnt > 64) cnt = 64;
        int j = 0;
        for (; j + 4 <= cnt; j += 4) {
            float2 a0 = mybuf[j], a1 = mybuf[j + 1], a2 = mybuf[j + 2], a3 = mybuf[j + 3];
            float x0 = __uint_as_float(((unsigned)(unsigned short)xp2b[(long)__float_as_int(a0.y) * 64 + lane]) << 16);
            float x1 = __uint_as_float(((unsigned)(unsigned short)xp2b[(long)__float_as_int(a1.y) * 64 + lane]) << 16);
            float x2 = __uint_as_float(((unsigned)(unsigned short)xp2b[(long)__float_as_int(a2.y) * 64 + lane]) << 16);
            float x3 = __uint_as_float(((unsigned)(unsigned short)xp2b[(long)__float_as_int(a3.y) * 64 + lane]) << 16);
            acc = fmaf(a0.x, x0, acc);
            acc = fmaf(a1.x, x1, acc);
            acc = fmaf(a2.x, x2, acc);
            acc = fmaf(a3.x, x3, acc);
        }
        for (; j < cnt; ++j) {
            float2 a = mybuf[j];
            acc = fmaf(a.x, __uint_as_float(((unsigned)(unsigned short)xp2b[(long)__float_as_int(a.y) * 64 + lane]) << 16), acc);
        }
    }
    h2[(long)n * 64 + lane] = acc / l + ldf(b2v, lane, fp32);
}

// ---------------- mean pool ----------------

__global__ __launch_bounds__(64) void pool_k(const float* __restrict__ h2,
                                             const int* __restrict__ batch,
                                             float* __restrict__ pooled,
                                             float* __restrict__ counts) {
    const int c = threadIdx.x;
    int lo = blockIdx.x * POOL_CHUNK;
    int hi = lo + POOL_CHUNK;
    if (hi > N_NODESC) hi = N_NODESC;
    if (lo >= N_NODESC) return;
    int cur = batch[lo];
    float acc = 0.f;
    int cnt = 0;
    for (int i = lo; i < hi; ++i) {
        int g = batch[i];
        if (g != cur) {
            atomicAdd(&pooled[cur * 64 + c], acc);
            if (c == 0) atomicAdd(&counts[cur], (float)cnt);
            acc = 0.f; cnt = 0; cur = g;
        }
        acc += h2[(long)i * 64 + c];
        cnt++;
    }
    atomicAdd(&pooled[cur * 64 + c], acc);
    if (c == 0) atomicAdd(&counts[cur], (float)cnt);
}

// ---------------- decoder MLP ----------------

__global__ __launch_bounds__(64) void dec_k(const float* __restrict__ pooled,
                                            const float* __restrict__ counts,
                                            const void* __restrict__ Wd1, const void* __restrict__ bd1,
                                            const void* __restrict__ Wd2, const void* __restrict__ bd2,
                                            const int* __restrict__ flags,
                                            void* __restrict__ out) {
    const int fp32 = flags[0];
    const int g = blockIdx.x, j = threadIdx.x;
    __shared__ float p[64], dh[64];
    float cnt = counts[g];
    cnt = cnt < 1.f ? 1.f : cnt;
    p[j] = pooled[g * 64 + j] / cnt;
    __syncthreads();
    float acc = ldf(bd1, j, fp32);
    for (int k = 0; k < 64; ++k) acc += p[k] * ldf(Wd1, k * 64 + j, fp32);
    dh[j] = acc > 0.f ? acc : 0.f;
    __syncthreads();
    if (j < 32) {
        float o = ldf(bd2, j, fp32);
        for (int k = 0; k < 64; ++k) o += dh[k] * ldf(Wd2, k * 32 + j, fp32);
        if (fp32) ((float*)out)[g * 32 + j] = o;
        else      ((bf16*)out)[g * 32 + j] = __float2bfloat16(o);
    }
}

extern "C" void kernel_launch(void* const* d_in, const int* in_sizes, int n_in,
                              void* d_out, int out_size, void* d_ws, size_t ws_size,
                              hipStream_t stream) {
    (void)in_sizes; (void)n_in; (void)out_size; (void)ws_size;
    const void* prot = d_in[0];
    const void* sp   = d_in[1];
    const void* lri  = d_in[2];
    const void* eidx = d_in[3];
    const void* batch= d_in[4];
    const void* W1   = d_in[5];
    const void* as1  = d_in[6];
    const void* ad1  = d_in[7];
    const void* b1   = d_in[8];
    const void* W2   = d_in[9];
    const void* as2  = d_in[10];
    const void* ad2  = d_in[11];
    const void* b2v  = d_in[12];
    const void* Wd1  = d_in[13];
    const void* bd1  = d_in[14];
    const void* Wd2  = d_in[15];
    const void* bd2  = d_in[16];

    char* w = (char*)d_ws;
    auto alloc = [&](size_t bytes) -> void* {
        char* p = w;
        w += (bytes + 255) & ~(size_t)255;
        return (void*)p;
    };
    int*   flags     = (int*)alloc(2 * 4);
    int*   edges32   = (int*)alloc((size_t)2 * N_EDGESC * 4);
    int*   batch32   = (int*)alloc((size_t)N_NODESC * 4);
    int*   deg       = (int*)alloc((size_t)N_NODESC * 4);
    int*   row_start = (int*)alloc((size_t)(N_NODESC + 1) * 4);
    int*   cursor    = (int*)alloc((size_t)N_NODESC * 4);
    int*   blocksum  = (int*)alloc((size_t)SCAN_NB * 4);
    int*   blockoff  = (int*)alloc((size_t)SCAN_NB * 4);
    int*   col       = (int*)alloc((size_t)N_EDGESC * 4);
    short* w1f       = (short*)alloc((size_t)16384 * 2);
    float* w1r       = (float*)alloc((size_t)256 * 4);
    short* w2f       = (short*)alloc((size_t)8192 * 2);
    float* xp1       = (float*)alloc((size_t)N_NODESC * 128 * 4);
    short* xp1b      = (short*)alloc((size_t)N_NODESC * 128 * 2);
    float* alsrc1    = (float*)alloc((size_t)N_NODESC * 2 * 4);
    float* aldst1    = (float*)alloc((size_t)N_NODESC * 2 * 4);
    short* h1b       = (short*)alloc((size_t)N_NODESC * 128 * 2);
    float* xp2       = (float*)alloc((size_t)N_NODESC * 64 * 4);
    short* xp2b      = (short*)alloc((size_t)N_NODESC * 64 * 2);
    float* alsrc2    = (float*)alloc((size_t)N_NODESC * 4);
    float* aldst2    = (float*)alloc((size_t)N_NODESC * 4);
    float* h2        = (float*)alloc((size_t)N_NODESC * 64 * 4);
    float* pooled    = (float*)alloc((size_t)NUM_GRAPHSC * 64 * 4);
    float* counts    = (float*)alloc((size_t)NUM_GRAPHSC * 4);

    detect_k<<<1, 64, 0, stream>>>(prot, eidx, flags);
    prep_k<<<97, 256, 0, stream>>>(W1, W2, flags, w1f, w1r, w2f);
    zero_k<<<(N_NODESC + 255) / 256, 256, 0, stream>>>(deg, N_NODESC);
    zero_k<<<(NUM_GRAPHSC * 64 + 255) / 256, 256, 0, stream>>>((int*)pooled, NUM_GRAPHSC * 64);
    zero_k<<<1, 256, 0, stream>>>((int*)counts, NUM_GRAPHSC);
    cvt_hist_k<<<(N_EDGESC + 255) / 256, 256, 0, stream>>>(eidx, edges32, deg, flags);
    cvt_batch_k<<<(N_NODESC + 255) / 256, 256, 0, stream>>>(batch, batch32, flags);

    const int* srcv = edges32;
    const int* dstv = edges32 + N_EDGESC;

    partial_k<<<SCAN_NB, SCAN_B, 0, stream>>>(deg, blocksum);
    scanpart_k<<<1, SCAN_B, 0, stream>>>(blocksum, blockoff);
    scanwrite_k<<<SCAN_NB, SCAN_B, 0, stream>>>(deg, blockoff, row_start, cursor);
    {
        const int nchunk = (N_EDGESC + EPB - 1) / EPB;
        scatter_k<<<nchunk * 8, 256, 0, stream>>>(srcv, dstv, cursor, col);
    }

    const int nblk = (N_NODESC + 31) / 32;
    gemm1_k<<<nblk, 256, 0, stream>>>(prot, sp, lri, w1f, w1r, flags, xp1, xp1b);
    logits1_k<<<(N_NODESC + 3) / 4, 256, 0, stream>>>(xp1, as1, ad1, flags, alsrc1, aldst1);
    agg1_k<<<(N_NODESC + 3) / 4, 256, 0, stream>>>(row_start, col, (const unsigned*)xp1b,
                                                   (const float2*)alsrc1, aldst1, b1, flags,
                                                   (unsigned*)h1b);
    gemm2_k<<<nblk, 256, 0, stream>>>((const unsigned*)h1b, w2f, xp2, xp2b);
    logits2_k<<<(N_NODESC + 3) / 4, 256, 0, stream>>>(xp2, as2, ad2, flags, alsrc2, aldst2);
    agg2_k<<<(N_NODESC + 3) / 4, 256, 0, stream>>>(row_start, col, xp2b, alsrc2, aldst2, b2v, flags, h2);
    pool_k<<<(N_NODESC + POOL_CHUNK - 1) / POOL_CHUNK, 64, 0, stream>>>(h2, batch32, pooled, counts);
    dec_k<<<NUM_GRAPHSC, 64, 0, stream>>>(pooled, counts, Wd1, bd1, Wd2, bd2, flags, d_out);
}